// Round 9
// baseline (307.950 us; speedup 1.0000x reference)
//
#include <hip/hip_runtime.h>
#include <stdint.h>

#define N_NODES 3072
#define D_IN    256
#define HIDDEN  384
#define HEADS   6
#define NH1     64
#define C1      1152   // 3*HIDDEN
#define C2      768    // 3*D_IN
#define QS      6      // j-splits for the sent branch (sect/doc get 1)
#define LOG2E   1.4426950408889634f

typedef __bf16 bf16;
typedef __bf16 bf16x8 __attribute__((ext_vector_type(8)));
typedef __bf16 bf16x4 __attribute__((ext_vector_type(4)));
typedef float  f32x4  __attribute__((ext_vector_type(4)));

typedef __attribute__((address_space(1))) const unsigned int as1_u32;
typedef __attribute__((address_space(3))) unsigned int as3_u32;

__device__ __forceinline__ void gload_lds16(const void* g, void* l) {
  __builtin_amdgcn_global_load_lds((as1_u32*)g, (as3_u32*)l, 16, 0, 0);
}
__device__ __forceinline__ void gload_lds4(const void* g, void* l) {
  __builtin_amdgcn_global_load_lds((as1_u32*)g, (as3_u32*)l, 4, 0, 0);
}

__device__ __forceinline__ void atomAddF(float* p, float v) {
  __hip_atomic_fetch_add(p, v, __ATOMIC_RELAXED, __HIP_MEMORY_SCOPE_AGENT);
}
__device__ __forceinline__ float fexp2(float x) {   // D = 2^S0
  float r; asm("v_exp_f32 %0, %1" : "=v"(r) : "v"(x)); return r;
}
// 32-aligned chunk boundary: q in [0,Qb]; B(0) floors jlo, B(Qb) ceils jhi.
__device__ __forceinline__ int bnd32(int jlo, int jhi, int len, int q, int Qb) {
  return (q >= Qb) ? ((jhi + 31) & ~31) : ((jlo + (len * q) / Qb) & ~31);
}

// ---------------------------------------------------------------- merged: cast fp32->bf16 + adj -> transposed byte mask adjT[mo][row]
struct CastArgs {
  const float* src[11];
  bf16*        dst[11];
  int          cum4[12];
  int          castN;     // # cast blocks; blocks beyond do adj transpose tiles
};

__global__ __launch_bounds__(256) void prep_kernel(CastArgs A,
                                                   const int* __restrict__ adj,
                                                   unsigned char* __restrict__ adjT) {
  if ((int)blockIdx.x < A.castN) {
    int g = blockIdx.x * 256 + threadIdx.x;
    int j = 0;
#pragma unroll
    for (int k = 1; k < 11; ++k) j += (g >= A.cum4[k]);
    int e = (g - A.cum4[j]) * 4;
    float4 v = *(const float4*)(A.src[j] + e);
    bf16x4 o = { (bf16)v.x, (bf16)v.y, (bf16)v.z, (bf16)v.w };
    *(bf16x4*)(A.dst[j] + e) = o;
    return;
  }
  // adj transpose: 384 blocks = (48 row-blocks) x (8 j-blocks of 384 j = 48 mo)
  int blk = blockIdx.x - A.castN;
  int rb = blk >> 3, jb = blk & 7;
  int row0 = rb * 64, jbase = jb * 384;
  __shared__ unsigned char tile[48][64];   // [mo_local][row_local]
  int wave = threadIdx.x >> 6, lane = threadIdx.x & 63;
#pragma unroll
  for (int rr = 0; rr < 16; ++rr) {
    int row = wave * 16 + rr;
    const int* ar = adj + (size_t)(row0 + row) * N_NODES + jbase;
#pragma unroll
    for (int it = 0; it < 6; ++it) {     // 6 x 64 = 384 j
      unsigned long long m = __ballot(ar[it * 64 + lane] != 0);
      if (lane < 8) tile[it * 8 + lane][row] = (unsigned char)(m >> (lane * 8));
    }
  }
  __syncthreads();
  // coalesced write-out: 48x64 bytes = 768 u32; 3 per thread
  const unsigned int* tu = (const unsigned int*)&tile[0][0];
  unsigned int* gu = (unsigned int*)adjT;
#pragma unroll
  for (int k = 0; k < 3; ++k) {
    int idx = k * 256 + threadIdx.x;
    int mo = idx >> 4, rw = idx & 15;
    gu[((size_t)((jbase >> 3) + mo)) * (N_NODES / 4) + (row0 >> 2) + rw] = tu[mo * 16 + rw];
  }
}

// ---------------------------------------------------------------- pack g[j][f] -> gP[j/8][f][8] + colmeans (+ layer1 head-proj fold)
template<int C, bool FOLD>
__global__ __launch_bounds__(256) void pack_kernel(const bf16* __restrict__ src,
                                                   bf16* __restrict__ dst,
                                                   float* __restrict__ gm,
                                                   const float* __restrict__ pa0,
                                                   const float* __restrict__ pa1,
                                                   const float* __restrict__ pa2,
                                                   float* __restrict__ elp,
                                                   float* __restrict__ eln,
                                                   float* __restrict__ erp,
                                                   float* __restrict__ ern) {
  __shared__ bf16 t[64][72];
  int j0 = blockIdx.x * 64, f0 = blockIdx.y * 64;
  int rr = threadIdx.x >> 4;
  int cc = (threadIdx.x & 15) * 4;
#pragma unroll
  for (int p = 0; p < 4; ++p) {
    int r = p * 16 + rr;
    *(bf16x4*)&t[r][cc] = *(const bf16x4*)&src[(size_t)(j0 + r) * C + f0 + cc];
  }
  __syncthreads();
  int f = threadIdx.x & 63, g = threadIdx.x >> 6;
#pragma unroll
  for (int q = 0; q < 2; ++q) {
    int p = g * 2 + q;
    bf16x8 v = { t[p*8+0][f], t[p*8+1][f], t[p*8+2][f], t[p*8+3][f],
                 t[p*8+4][f], t[p*8+5][f], t[p*8+6][f], t[p*8+7][f] };
    *(bf16x8*)&dst[ ((size_t)((j0 >> 3) + p) * C + f0 + f) * 8 ] = v;
  }
  float s = 0.f;
#pragma unroll
  for (int k = 0; k < 16; ++k) s += (float)t[g * 16 + k][f];
  atomAddF(&gm[f0 + f], s * (1.0f / N_NODES));
  if constexpr (FOLD) {
    // layer1 head-projection: this f-tile IS combo cmb's full 64-f slice.
    int cmb = f0 >> 6;
    int b = cmb / 6;
    const float* a = (b == 0) ? pa0 : (b == 1) ? pa1 : pa2;
    int r = threadIdx.x >> 2;
    int part = (threadIdx.x & 3) * 16;
    float dl = 0.f, dr = 0.f;
#pragma unroll
    for (int k = 0; k < 16; ++k) {
      float gv = (float)t[r][part + k];
      dl += gv * a[part + k];
      dr += gv * a[64 + part + k];
    }
    dl += __shfl_xor(dl, 1, 64); dr += __shfl_xor(dr, 1, 64);
    dl += __shfl_xor(dl, 2, 64); dr += __shfl_xor(dr, 2, 64);
    if ((threadIdx.x & 3) == 0) {
      int o = cmb * N_NODES + j0 + r;
      elp[o] = fexp2(dl * LOG2E);
      eln[o] = fexp2(0.2f * dl * LOG2E);
      erp[o] = fexp2(dr * LOG2E);
      ern[o] = fexp2(0.2f * dr * LOG2E);
    }
  }
}

// ---------------------------------------------------------------- head projections (layer2 only) -> exp-factor arrays
template<int NCPB, int NH>
__global__ __launch_bounds__(256) void head_proj_kernel(
    const bf16* __restrict__ g, int ldg,
    const float* __restrict__ a0, const float* __restrict__ a1, const float* __restrict__ a2,
    float* __restrict__ elp, float* __restrict__ eln,
    float* __restrict__ erp, float* __restrict__ ern) {
  int c = blockIdx.y;
  int i = blockIdx.x * 16 + (threadIdx.x >> 4);
  int b = c / NCPB;
  const float* a = (b == 0) ? a0 : (b == 1) ? a1 : a2;
  int f0 = (threadIdx.x & 15) * (NH / 16);
  const bf16* gr = g + (size_t)i * ldg + c * NH + f0;
  float accl = 0.f, accr = 0.f;
#pragma unroll
  for (int k = 0; k < NH / 16; k += 4) {
    bf16x4 v = *(const bf16x4*)&gr[k];
#pragma unroll
    for (int e = 0; e < 4; ++e) {
      float gv = (float)v[e];
      accl += gv * a[f0 + k + e];
      accr += gv * a[NH + f0 + k + e];
    }
  }
#pragma unroll
  for (int m = 1; m < 16; m <<= 1) {
    accl += __shfl_xor(accl, m, 64);
    accr += __shfl_xor(accr, m, 64);
  }
  if ((threadIdx.x & 15) == 0) {
    int o = c * N_NODES + i;
    elp[o] = fexp2(accl * LOG2E);
    eln[o] = fexp2(0.2f * accl * LOG2E);
    erp[o] = fexp2(accr * LOG2E);
    ern[o] = fexp2(0.2f * accr * LOG2E);
  }
}

// ---------------------------------------------------------------- GEMM 64x64 tile, single-barrier LDS double-buffer
template<bool BIAS, bool LEAKY, bool RES, bool F32OUT>
__global__ __launch_bounds__(256) void gemm64_kernel(
    const bf16* __restrict__ A, int lda, int aZoff,
    const bf16* __restrict__ B0, const bf16* __restrict__ B1, const bf16* __restrict__ B2,
    int ldb, void* __restrict__ Cout, int ldc, int cZoff, int K,
    const float* __restrict__ bias, const float* __restrict__ res) {
  __shared__ bf16 As[2 * 64 * 64];
  __shared__ bf16 Bs[2 * 64 * 64];
  int z = blockIdx.z;
  const bf16* Ab = A + (size_t)z * aZoff;
  const bf16* Bb = (z == 0) ? B0 : (z == 1) ? B1 : B2;
  int m0 = blockIdx.x * 64, n0 = blockIdx.y * 64;
  int tid = threadIdx.x;
  int lane = tid & 63, wave = tid >> 6;
  int wm = wave >> 1, wn = wave & 1;
  int l15 = lane & 15, lk = lane >> 4;
  int r0 = tid >> 3, p0 = tid & 7, q0 = p0 ^ (r0 & 7);
  int r1 = (256 + tid) >> 3, p1 = tid & 7, q1 = p1 ^ (r1 & 7);
  bf16x8 ra0, ra1, rb0, rb1;
  auto gload = [&](int kt) {
    const bf16* ab = Ab + (size_t)kt * 64;
    const bf16* bb = Bb + (size_t)kt * 64;
    ra0 = *(const bf16x8*)&ab[(size_t)(m0 + r0) * lda + q0 * 8];
    ra1 = *(const bf16x8*)&ab[(size_t)(m0 + r1) * lda + q1 * 8];
    rb0 = *(const bf16x8*)&bb[(size_t)(n0 + r0) * ldb + q0 * 8];
    rb1 = *(const bf16x8*)&bb[(size_t)(n0 + r1) * ldb + q1 * 8];
  };
  auto sstore = [&](int buf) {
    bf16* as = As + buf * 4096;
    bf16* bs = Bs + buf * 4096;
    *(bf16x8*)&as[r0 * 64 + p0 * 8] = ra0;
    *(bf16x8*)&as[r1 * 64 + p1 * 8] = ra1;
    *(bf16x8*)&bs[r0 * 64 + p0 * 8] = rb0;
    *(bf16x8*)&bs[r1 * 64 + p1 * 8] = rb1;
  };
  f32x4 acc[2][2] = {};
  int nk = K >> 6;
  gload(0);
  sstore(0);
  __syncthreads();
  for (int kt = 0; kt < nk; ++kt) {
    bool more = (kt + 1) < nk;
    if (more) gload(kt + 1);
    const bf16* as = As + (kt & 1) * 4096;
    const bf16* bs = Bs + (kt & 1) * 4096;
#pragma unroll
    for (int s = 0; s < 2; ++s) {
      bf16x8 af[2], bfr[2];
      int u = s * 4 + lk;
#pragma unroll
      for (int mi = 0; mi < 2; ++mi) {
        int r = wm * 32 + mi * 16 + l15;
        af[mi] = *(const bf16x8*)&as[r * 64 + (u ^ (r & 7)) * 8];
      }
#pragma unroll
      for (int ni = 0; ni < 2; ++ni) {
        int r = wn * 32 + ni * 16 + l15;
        bfr[ni] = *(const bf16x8*)&bs[r * 64 + (u ^ (r & 7)) * 8];
      }
#pragma unroll
      for (int mi = 0; mi < 2; ++mi)
#pragma unroll
        for (int ni = 0; ni < 2; ++ni)
          acc[mi][ni] = __builtin_amdgcn_mfma_f32_16x16x32_bf16(af[mi], bfr[ni], acc[mi][ni], 0, 0, 0);
    }
    if (more) sstore((kt + 1) & 1);
    __syncthreads();
  }
#pragma unroll
  for (int mi = 0; mi < 2; ++mi)
#pragma unroll
    for (int ni = 0; ni < 2; ++ni)
#pragma unroll
      for (int r = 0; r < 4; ++r) {
        int i = m0 + wm * 32 + mi * 16 + lk * 4 + r;
        int col = z * cZoff + n0 + wn * 32 + ni * 16 + l15;
        float v = acc[mi][ni][r];
        if (BIAS) v += bias[col];
        if (LEAKY) v = (v >= 0.f) ? v : 0.01f * v;
        if (RES) v += res[(size_t)i * ldc + col];
        if (F32OUT) ((float*)Cout)[(size_t)i * ldc + col] = v;
        else        ((bf16*)Cout)[(size_t)i * ldc + col] = (bf16)v;
      }
}

// ---------------------------------------------------------------- attention: LDS-staged 2-phase pipeline
// Mask: single transposed byte array adjT[mo][row], branch range applied
// arithmetically (rangeByte from jlo/jhi).
template<bool L1>
__global__ __launch_bounds__(256, 2) void att_kernel(
    const bf16* __restrict__ gP,
    const float* __restrict__ elpA, const float* __restrict__ elnA,
    const float* __restrict__ erpA, const float* __restrict__ ernA,
    const unsigned char* __restrict__ adjT,
    const int* __restrict__ dnum, const int* __restrict__ snum,
    float* __restrict__ accP, float* __restrict__ lP) {
  constexpr int C = L1 ? C1 : C2;
  int c = blockIdx.y;
  int b = L1 ? (c / 6) : (c >> 2);
  int colbase = L1 ? c * 64 : (b * 256 + (c & 3) * 64);
  int sidx = L1 ? c : b;
  int q = blockIdx.z;
  int Qb = (b == 0) ? QS : 1;
  if (q >= Qb) return;
  int dn = dnum[0], sn = snum[0];
  int bb1 = N_NODES - sn - dn, bb2 = N_NODES - dn;
  int jlo = (b == 0) ? 0 : (b == 1) ? bb1 : bb2;
  int jhi = (b == 0) ? bb1 : (b == 1) ? bb2 : N_NODES;
  int len = jhi - jlo;
  int wlo = bnd32(jlo, jhi, len, q, Qb);
  int whi = bnd32(jlo, jhi, len, q + 1, Qb);
  if (wlo >= whi) return;

  __shared__ bf16  sgP[2][8][64 * 8];   // [buf][octet][col][8]
  __shared__ float serp[2][64];
  __shared__ float sern[2][64];

  int wave = threadIdx.x >> 6, lane = threadIdx.x & 63;
  int l15 = lane & 15, lk = lane >> 4;
  int row0 = blockIdx.x * 256 + wave * 64;   // this wave's 64 rows
  float elp[4], eln[4];
#pragma unroll
  for (int rg = 0; rg < 4; ++rg) {
    int ip = row0 + rg * 16 + l15;
    elp[rg] = elpA[sidx * N_NODES + ip];
    eln[rg] = elnA[sidx * N_NODES + ip];
  }
  const float* erpB = erpA + sidx * N_NODES;
  const float* ernB = ernA + sidx * N_NODES;
  const bf16* gPcol = gP + (size_t)colbase * 8;
  bf16x8 ones;
#pragma unroll
  for (int e = 0; e < 8; ++e) ones[e] = (bf16)1.0f;
  f32x4 acc[4][4] = {};
  f32x4 accl[4] = {};

  auto stage = [&](int buf, int cb) {
    int mo0 = cb >> 3;
#pragma unroll
    for (int k = 0; k < 2; ++k) {
      int ml = wave * 2 + k;
      if ((mo0 + ml) * 8 < whi)
        gload_lds16(gPcol + ((size_t)(mo0 + ml) * C + lane) * 8, &sgP[buf][ml][0]);
    }
    if (wave == 0) gload_lds4(erpB + cb + lane, &serp[buf][0]);
    if (wave == 1) gload_lds4(ernB + cb + lane, &sern[buf][0]);
  };

  int buf = 0;
  stage(0, wlo);
  asm volatile("s_waitcnt vmcnt(0)" ::: "memory");
  __syncthreads();
  for (int cb = wlo; cb < whi; cb += 64) {
    int nb = cb + 64;
    if (nb < whi) stage(buf ^ 1, nb);    // in flight during compute below
#pragma unroll
    for (int h = 0; h < 2; ++h) {
      int jt = cb + h * 32;
      if (jt >= whi) break;
      int lj = h * 32 + lk * 8;          // lane's local j-octet offset
      int oct = h * 4 + lk;
      int mo = (jt >> 3) + lk;
      int j0o = mo << 3;
      int lo = min(max(jlo - j0o, 0), 8);
      int hi = min(max(jhi - j0o, 0), 8);
      unsigned int rb_ = ((1u << hi) - 1u) & ~((1u << lo) - 1u);
      f32x4 pv0 = *(const f32x4*)&serp[buf][lj];
      f32x4 pv1 = *(const f32x4*)&serp[buf][lj + 4];
      f32x4 nv0 = *(const f32x4*)&sern[buf][lj];
      f32x4 nv1 = *(const f32x4*)&sern[buf][lj + 4];
      bf16x8 bf0 = *(const bf16x8*)&sgP[buf][oct][(0 * 16 + l15) * 8];
      bf16x8 bf1 = *(const bf16x8*)&sgP[buf][oct][(1 * 16 + l15) * 8];
      bf16x8 bf2 = *(const bf16x8*)&sgP[buf][oct][(2 * 16 + l15) * 8];
      bf16x8 bf3 = *(const bf16x8*)&sgP[buf][oct][(3 * 16 + l15) * 8];
      const unsigned char* mT = adjT + (size_t)mo * N_NODES + row0;
#pragma unroll
      for (int rg = 0; rg < 4; ++rg) {
        unsigned int mb = mT[rg * 16 + l15] & rb_;
        bf16x8 a8;
#pragma unroll
        for (int e = 0; e < 8; ++e) {
          float pvv = (e < 4) ? pv0[e & 3] : pv1[e & 3];
          float nvv = (e < 4) ? nv0[e & 3] : nv1[e & 3];
          float z = elp[rg] * pvv;
          float w = eln[rg] * nvv;
          float p = (z >= 1.f) ? z : w;
          p = ((mb >> e) & 1u) ? p : 0.f;
          a8[e] = (bf16)p;
        }
        acc[rg][0] = __builtin_amdgcn_mfma_f32_16x16x32_bf16(a8, bf0, acc[rg][0], 0, 0, 0);
        acc[rg][1] = __builtin_amdgcn_mfma_f32_16x16x32_bf16(a8, bf1, acc[rg][1], 0, 0, 0);
        acc[rg][2] = __builtin_amdgcn_mfma_f32_16x16x32_bf16(a8, bf2, acc[rg][2], 0, 0, 0);
        acc[rg][3] = __builtin_amdgcn_mfma_f32_16x16x32_bf16(a8, bf3, acc[rg][3], 0, 0, 0);
        accl[rg]   = __builtin_amdgcn_mfma_f32_16x16x32_bf16(a8, ones, accl[rg], 0, 0, 0);
      }
    }
    asm volatile("s_waitcnt vmcnt(0)" ::: "memory");
    __syncthreads();                      // next buffer fully staged; safe to swap
    buf ^= 1;
  }

  int slot = (b == 0) ? (c * QS + q) : (L1 ? (36 + (c - 6)) : (24 + (c - 4)));
  float* ap = accP + ((size_t)slot * N_NODES + row0) * 64;
#pragma unroll
  for (int rg = 0; rg < 4; ++rg)
#pragma unroll
    for (int nf = 0; nf < 4; ++nf)
#pragma unroll
      for (int r = 0; r < 4; ++r)
        ap[(rg * 16 + lk * 4 + r) * 64 + nf * 16 + l15] = acc[rg][nf][r];
  if (l15 == 0) {
#pragma unroll
    for (int rg = 0; rg < 4; ++rg)
#pragma unroll
      for (int r = 0; r < 4; ++r)
        lP[(size_t)slot * N_NODES + row0 + rg * 16 + lk * 4 + r] = accl[rg][r];
  }
}

// ---------------------------------------------------------------- finalize layer 1: sum slices, /l (or gmean), ELU
__global__ __launch_bounds__(256) void fin1_kernel(
    const float* __restrict__ accP, const float* __restrict__ lP,
    const float* __restrict__ gm, const int* __restrict__ dnum, const int* __restrict__ snum,
    bf16* __restrict__ out1) {
  int t = blockIdx.x * 256 + threadIdx.x;
  int i = t / (C1 / 8), f0 = (t - i * (C1 / 8)) * 8;
  int c = f0 >> 6;
  int b = c / 6;
  int dn = dnum[0], sn = snum[0];
  int bb1 = N_NODES - sn - dn, bb2 = N_NODES - dn;
  int jlo = (b == 0) ? 0 : (b == 1) ? bb1 : bb2;
  int jhi = (b == 0) ? bb1 : (b == 1) ? bb2 : N_NODES;
  int len = jhi - jlo;
  int Qb = (b == 0) ? QS : 1;
  float l = 0.f;
  float a[8] = {0.f,0.f,0.f,0.f,0.f,0.f,0.f,0.f};
  if (len > 0) {
    for (int q = 0; q < Qb; ++q) {
      if (bnd32(jlo, jhi, len, q, Qb) >= bnd32(jlo, jhi, len, q + 1, Qb)) continue;
      int slot = (b == 0) ? (c * QS + q) : (36 + (c - 6));
      l += lP[(size_t)slot * N_NODES + i];
      const float* ap = &accP[((size_t)slot * N_NODES + i) * 64 + (f0 & 63)];
      f32x4 v0 = *(const f32x4*)ap, v1 = *(const f32x4*)(ap + 4);
#pragma unroll
      for (int e = 0; e < 4; ++e) { a[e] += v0[e]; a[e + 4] += v1[e]; }
    }
  }
  float inv = (l > 0.f) ? 1.f / l : 0.f;
  bf16x8 o;
#pragma unroll
  for (int e = 0; e < 8; ++e) {
    float v = (l > 0.f) ? a[e] * inv : gm[f0 + e];
    v = (v > 0.f) ? v : (__expf(v) - 1.f);   // ELU
    o[e] = (bf16)v;
  }
  *(bf16x8*)&out1[(size_t)i * C1 + f0] = o;
}

// ---------------------------------------------------------------- finalize layer 2: sum slices, /l (or gmean), +residual -> fused
__global__ __launch_bounds__(256) void fin2_kernel(
    const float* __restrict__ accP, const float* __restrict__ lP,
    const float* __restrict__ gm, const float* __restrict__ feat,
    const int* __restrict__ dnum, const int* __restrict__ snum,
    bf16* __restrict__ fused) {
  int t = blockIdx.x * 256 + threadIdx.x;
  int i = t / (C2 / 8), f0 = (t - i * (C2 / 8)) * 8;
  int b = f0 >> 8;
  int fi = f0 & 255;
  int fc = (f0 >> 6) & 3;
  int c = b * 4 + fc;
  int dn = dnum[0], sn = snum[0];
  int bb1 = N_NODES - sn - dn, bb2 = N_NODES - dn;
  int jlo = (b == 0) ? 0 : (b == 1) ? bb1 : bb2;
  int jhi = (b == 0) ? bb1 : (b == 1) ? bb2 : N_NODES;
  int len = jhi - jlo;
  int Qb = (b == 0) ? QS : 1;
  float l = 0.f;
  float a[8] = {0.f,0.f,0.f,0.f,0.f,0.f,0.f,0.f};
  if (len > 0) {
    for (int q = 0; q < Qb; ++q) {
      if (bnd32(jlo, jhi, len, q, Qb) >= bnd32(jlo, jhi, len, q + 1, Qb)) continue;
      int slot = (b == 0) ? (c * QS + q) : (24 + (c - 4));
      l += lP[(size_t)slot * N_NODES + i];
      const float* ap = &accP[((size_t)slot * N_NODES + i) * 64 + (f0 & 63)];
      f32x4 v0 = *(const f32x4*)ap, v1 = *(const f32x4*)(ap + 4);
#pragma unroll
      for (int e = 0; e < 4; ++e) { a[e] += v0[e]; a[e + 4] += v1[e]; }
    }
  }
  float inv = (l > 0.f) ? 1.f / l : 0.f;
  bf16x8 o;
#pragma unroll
  for (int e = 0; e < 8; ++e) {
    float v = (l > 0.f) ? a[e] * inv : gm[f0 + e];
    v += feat[(size_t)i * D_IN + fi + e];
    o[e] = (bf16)v;
  }
  *(bf16x8*)&fused[(size_t)i * C2 + (2 - b) * D_IN + fi] = o;
}

// ---------------------------------------------------------------- launch
extern "C" void kernel_launch(void* const* d_in, const int* in_sizes, int n_in,
                              void* d_out, int out_size, void* d_ws, size_t ws_size,
                              hipStream_t stream) {
  (void)in_sizes; (void)n_in; (void)out_size; (void)ws_size;
  const float* feature = (const float*)d_in[0];
  const int*   adj     = (const int*)d_in[1];
  const int*   dnum    = (const int*)d_in[2];
  const int*   snum    = (const int*)d_in[3];
  const float* W1s = (const float*)d_in[4];  const float* a1s = (const float*)d_in[5];
  const float* W2s = (const float*)d_in[6];  const float* a2s = (const float*)d_in[7];
  const float* W1e = (const float*)d_in[8];  const float* a1e = (const float*)d_in[9];
  const float* W2e = (const float*)d_in[10]; const float* a2e = (const float*)d_in[11];
  const float* W1d = (const float*)d_in[12]; const float* a1d = (const float*)d_in[13];
  const float* W2d = (const float*)d_in[14]; const float* a2d = (const float*)d_in[15];
  const float* fW  = (const float*)d_in[16]; const float* fB  = (const float*)d_in[17];
  const float* w0  = (const float*)d_in[18]; const float* b0  = (const float*)d_in[19];
  const float* w1  = (const float*)d_in[20]; const float* b1  = (const float*)d_in[21];
  const float* w2  = (const float*)d_in[22]; const float* b2  = (const float*)d_in[23];

  char* ws = (char*)d_ws;
  size_t off = 0;
  auto alloc = [&](size_t bytes) { void* p = ws + off; off += (bytes + 255) & ~(size_t)255; return p; };

  unsigned char* adjT = (unsigned char*)alloc((size_t)384 * N_NODES);  // [mo][row], 1.125 MB
  bf16* fbf   = (bf16*)alloc((size_t)N_NODES * D_IN * 2);
  bf16* w1b0  = (bf16*)alloc(HIDDEN * D_IN * 2);
  bf16* w1b1  = (bf16*)alloc(HIDDEN * D_IN * 2);
  bf16* w1b2  = (bf16*)alloc(HIDDEN * D_IN * 2);
  bf16* w2b0  = (bf16*)alloc(D_IN * HIDDEN * 2);
  bf16* w2b1  = (bf16*)alloc(D_IN * HIDDEN * 2);
  bf16* w2b2  = (bf16*)alloc(D_IN * HIDDEN * 2);
  bf16* wfusb = (bf16*)alloc(D_IN * C2 * 2);
  bf16* wf0b  = (bf16*)alloc(HIDDEN * D_IN * 2);
  bf16* wf1b  = (bf16*)alloc(HIDDEN * HIDDEN * 2);
  bf16* wf2b  = (bf16*)alloc(D_IN * HIDDEN * 2);
  bf16* g1    = (bf16*)alloc((size_t)N_NODES * C1 * 2);
  bf16* gP1   = (bf16*)alloc((size_t)N_NODES * C1 * 2);
  bf16* out1  = (bf16*)alloc((size_t)N_NODES * C1 * 2);
  bf16* g2    = (bf16*)alloc((size_t)N_NODES * C2 * 2);
  bf16* gP2   = (bf16*)alloc((size_t)N_NODES * C2 * 2);
  bf16* fusedB= (bf16*)alloc((size_t)N_NODES * C2 * 2);
  bf16* h0    = (bf16*)alloc((size_t)N_NODES * D_IN * 2);
  bf16* h1    = (bf16*)alloc((size_t)N_NODES * HIDDEN * 2);
  bf16* h2    = (bf16*)alloc((size_t)N_NODES * HIDDEN * 2);
  float* elp1 = (float*)alloc(18 * N_NODES * 4);
  float* eln1 = (float*)alloc(18 * N_NODES * 4);
  float* erp1 = (float*)alloc(18 * N_NODES * 4);
  float* ern1 = (float*)alloc(18 * N_NODES * 4);
  float* elp2 = (float*)alloc(3 * N_NODES * 4);
  float* eln2 = (float*)alloc(3 * N_NODES * 4);
  float* erp2 = (float*)alloc(3 * N_NODES * 4);
  float* ern2 = (float*)alloc(3 * N_NODES * 4);
  float* accU = (float*)alloc((size_t)48 * N_NODES * 64 * 4);  // 37.7 MB
  float* lU   = (float*)alloc((size_t)48 * N_NODES * 4);
  size_t zoff = off;
  float* gm1  = (float*)alloc(C1 * 4);
  float* gm2  = (float*)alloc(C2 * 4);
  size_t zbytes = off - zoff;

  hipMemsetAsync(ws + zoff, 0, zbytes, stream);

  // 1) casts + adj transpose (merged)
  CastArgs ca;
  {
    const float* srcs[11] = { feature, W1s, W1e, W1d, W2s, W2e, W2d, fW, w0, w1, w2 };
    bf16* dsts[11] = { fbf, w1b0, w1b1, w1b2, w2b0, w2b1, w2b2, wfusb, wf0b, wf1b, wf2b };
    int counts[11] = { N_NODES*D_IN, HIDDEN*D_IN, HIDDEN*D_IN, HIDDEN*D_IN,
                       D_IN*HIDDEN, D_IN*HIDDEN, D_IN*HIDDEN, D_IN*C2,
                       HIDDEN*D_IN, HIDDEN*HIDDEN, D_IN*HIDDEN };
    int cum = 0;
    for (int k = 0; k < 11; ++k) { ca.src[k] = srcs[k]; ca.dst[k] = dsts[k]; ca.cum4[k] = cum; cum += counts[k] / 4; }
    ca.cum4[11] = cum;
    ca.castN = cum / 256;
    prep_kernel<<<ca.castN + 384, 256, 0, stream>>>(ca, adj, adjT);
  }
  // 2) g1 = f @ W1^T (3 branches via z)
  gemm64_kernel<false,false,false,false><<<dim3(48,6,3), 256, 0, stream>>>(
      fbf, D_IN, 0, w1b0, w1b1, w1b2, D_IN, g1, C1, HIDDEN, D_IN, nullptr, nullptr);
  // 3) pack g1 -> gP1 (+colmean +layer1 head-proj fold)
  pack_kernel<C1,true><<<dim3(48,18), 256, 0, stream>>>(g1, gP1, gm1, a1s, a1e, a1d, elp1, eln1, erp1, ern1);
  // 4) attention 1 partials (LDS-staged 2-phase)
  att_kernel<true><<<dim3(12, 18, QS), 256, 0, stream>>>(gP1, elp1, eln1, erp1, ern1, adjT, dnum, snum, accU, lU);
  // 4b) finalize 1 (+ELU)
  fin1_kernel<<<N_NODES * (C1 / 8) / 256, 256, 0, stream>>>(accU, lU, gm1, dnum, snum, out1);
  // 5) g2 = out1 @ W2^T per branch
  gemm64_kernel<false,false,false,false><<<dim3(48,4,3), 256, 0, stream>>>(
      out1, C1, HIDDEN, w2b0, w2b1, w2b2, HIDDEN, g2, C2, D_IN, HIDDEN, nullptr, nullptr);
  // 6) pack g2 -> gP2 (+colmean)
  pack_kernel<C2,false><<<dim3(48,12), 256, 0, stream>>>(g2, gP2, gm2,
      nullptr, nullptr, nullptr, nullptr, nullptr, nullptr, nullptr);
  // 7) exp factors layer2
  head_proj_kernel<1, D_IN><<<dim3(192,3), 256, 0, stream>>>(g2, C2, a2s, a2e, a2d, elp2, eln2, erp2, ern2);
  // 8) attention 2 partials
  att_kernel<false><<<dim3(12, 12, QS), 256, 0, stream>>>(gP2, elp2, eln2, erp2, ern2, adjT, dnum, snum, accU, lU);
  // 8b) finalize 2 (+residual, writes fused [doc,sect,sent])
  fin2_kernel<<<N_NODES * (C2 / 8) / 256, 256, 0, stream>>>(accU, lU, gm2, feature, dnum, snum, fusedB);
  // 9) fusion: h0 = leaky(fused @ fW^T + fB)
  gemm64_kernel<true,true,false,false><<<dim3(48,4,1), 256, 0, stream>>>(
      fusedB, C2, 0, wfusb, wfusb, wfusb, C2, h0, D_IN, 0, C2, fB, nullptr);
  // 10) ffn0: h1 = leaky(h0 @ w0^T + b0)
  gemm64_kernel<true,true,false,false><<<dim3(48,6,1), 256, 0, stream>>>(
      h0, D_IN, 0, wf0b, wf0b, wf0b, D_IN, h1, HIDDEN, 0, D_IN, b0, nullptr);
  // 11) ffn1: h2 = leaky(h1 @ w1^T + b1)
  gemm64_kernel<true,true,false,false><<<dim3(48,6,1), 256, 0, stream>>>(
      h1, HIDDEN, 0, wf1b, wf1b, wf1b, HIDDEN, h2, HIDDEN, 0, HIDDEN, b1, nullptr);
  // 12) ffn2: out = leaky(h2 @ w2^T + b2) + f   (fp32 out)
  gemm64_kernel<true,true,true,true><<<dim3(48,4,1), 256, 0, stream>>>(
      h2, HIDDEN, 0, wf2b, wf2b, wf2b, HIDDEN, d_out, D_IN, 0, HIDDEN, b2, feature);
}

// Round 10
// 272.629 us; speedup vs baseline: 1.1296x; 1.1296x over previous
//
#include <hip/hip_runtime.h>
#include <stdint.h>

#define N_NODES 3072
#define D_IN    256
#define HIDDEN  384
#define HEADS   6
#define NH1     64
#define C1      1152   // 3*HIDDEN
#define C2      768    // 3*D_IN
#define QS      6      // j-splits for the sent branch (sect/doc get 1)
#define LOG2E   1.4426950408889634f

typedef __bf16 bf16;
typedef __bf16 bf16x8 __attribute__((ext_vector_type(8)));
typedef __bf16 bf16x4 __attribute__((ext_vector_type(4)));
typedef float  f32x4  __attribute__((ext_vector_type(4)));

typedef __attribute__((address_space(1))) const unsigned int as1_u32;
typedef __attribute__((address_space(3))) unsigned int as3_u32;

__device__ __forceinline__ void gload_lds16(const void* g, void* l) {
  __builtin_amdgcn_global_load_lds((as1_u32*)g, (as3_u32*)l, 16, 0, 0);
}
__device__ __forceinline__ void gload_lds4(const void* g, void* l) {
  __builtin_amdgcn_global_load_lds((as1_u32*)g, (as3_u32*)l, 4, 0, 0);
}

__device__ __forceinline__ void atomAddF(float* p, float v) {
  __hip_atomic_fetch_add(p, v, __ATOMIC_RELAXED, __HIP_MEMORY_SCOPE_AGENT);
}
__device__ __forceinline__ float fexp2(float x) {   // D = 2^S0
  float r; asm("v_exp_f32 %0, %1" : "=v"(r) : "v"(x)); return r;
}
// 32-aligned chunk boundary: q in [0,Qb]; B(0) floors jlo, B(Qb) ceils jhi.
__device__ __forceinline__ int bnd32(int jlo, int jhi, int len, int q, int Qb) {
  return (q >= Qb) ? ((jhi + 31) & ~31) : ((jlo + (len * q) / Qb) & ~31);
}

// ---------------------------------------------------------------- merged: cast fp32->bf16 + adj -> transposed byte mask adjT[mo][row]
struct CastArgs {
  const float* src[11];
  bf16*        dst[11];
  int          cum4[12];
  int          castN;     // # cast blocks; blocks beyond do adj transpose tiles
};

__global__ __launch_bounds__(256) void prep_kernel(CastArgs A,
                                                   const int* __restrict__ adj,
                                                   unsigned char* __restrict__ adjT) {
  if ((int)blockIdx.x < A.castN) {
    int g = blockIdx.x * 256 + threadIdx.x;
    int j = 0;
#pragma unroll
    for (int k = 1; k < 11; ++k) j += (g >= A.cum4[k]);
    int e = (g - A.cum4[j]) * 4;
    float4 v = *(const float4*)(A.src[j] + e);
    bf16x4 o = { (bf16)v.x, (bf16)v.y, (bf16)v.z, (bf16)v.w };
    *(bf16x4*)(A.dst[j] + e) = o;
    return;
  }
  // adj transpose: 288 blocks = (48 row-blocks x 64 rows) x (6 mo-blocks x 64 mo)
  // Arithmetic byte-build per thread (no ballot, no serialization); ILP-friendly.
  int blk = blockIdx.x - A.castN;
  int rb = blk / 6, jb = blk - rb * 6;
  int row0 = rb * 64, mo0 = jb * 64;
  __shared__ unsigned char tile[64][68];   // [mo_local][row_local], pad 68 -> bank-free
#pragma unroll
  for (int s = 0; s < 16; ++s) {
    int bI = s * 256 + threadIdx.x;        // byte index in 64x64 tile
    int row = bI >> 6, mo = bI & 63;
    const int4* p = (const int4*)(adj + (size_t)(row0 + row) * N_NODES + (size_t)(mo0 + mo) * 8);
    int4 v0 = p[0], v1 = p[1];
    unsigned int by = (unsigned)(v0.x != 0)        | ((unsigned)(v0.y != 0) << 1)
                    | ((unsigned)(v0.z != 0) << 2) | ((unsigned)(v0.w != 0) << 3)
                    | ((unsigned)(v1.x != 0) << 4) | ((unsigned)(v1.y != 0) << 5)
                    | ((unsigned)(v1.z != 0) << 6) | ((unsigned)(v1.w != 0) << 7);
    tile[mo][row] = (unsigned char)by;
  }
  __syncthreads();
  // coalesced write-out: 64x64 bytes = 1024 u32; 4 per thread
  unsigned int* gu = (unsigned int*)adjT;
#pragma unroll
  for (int k = 0; k < 4; ++k) {
    int idx = k * 256 + threadIdx.x;
    int mo = idx >> 4, rw = idx & 15;
    unsigned int w = *(const unsigned int*)&tile[mo][rw * 4];
    gu[(size_t)(mo0 + mo) * (N_NODES / 4) + (row0 >> 2) + rw] = w;
  }
}

// ---------------------------------------------------------------- pack g[j][f] -> gP[j/8][f][8] + colmeans (+ layer1 head-proj fold)
template<int C, bool FOLD>
__global__ __launch_bounds__(256) void pack_kernel(const bf16* __restrict__ src,
                                                   bf16* __restrict__ dst,
                                                   float* __restrict__ gm,
                                                   const float* __restrict__ pa0,
                                                   const float* __restrict__ pa1,
                                                   const float* __restrict__ pa2,
                                                   float* __restrict__ elp,
                                                   float* __restrict__ eln,
                                                   float* __restrict__ erp,
                                                   float* __restrict__ ern) {
  __shared__ bf16 t[64][72];
  int j0 = blockIdx.x * 64, f0 = blockIdx.y * 64;
  int rr = threadIdx.x >> 4;
  int cc = (threadIdx.x & 15) * 4;
#pragma unroll
  for (int p = 0; p < 4; ++p) {
    int r = p * 16 + rr;
    *(bf16x4*)&t[r][cc] = *(const bf16x4*)&src[(size_t)(j0 + r) * C + f0 + cc];
  }
  __syncthreads();
  int f = threadIdx.x & 63, g = threadIdx.x >> 6;
#pragma unroll
  for (int q = 0; q < 2; ++q) {
    int p = g * 2 + q;
    bf16x8 v = { t[p*8+0][f], t[p*8+1][f], t[p*8+2][f], t[p*8+3][f],
                 t[p*8+4][f], t[p*8+5][f], t[p*8+6][f], t[p*8+7][f] };
    *(bf16x8*)&dst[ ((size_t)((j0 >> 3) + p) * C + f0 + f) * 8 ] = v;
  }
  float s = 0.f;
#pragma unroll
  for (int k = 0; k < 16; ++k) s += (float)t[g * 16 + k][f];
  atomAddF(&gm[f0 + f], s * (1.0f / N_NODES));
  if constexpr (FOLD) {
    // layer1 head-projection: this f-tile IS combo cmb's full 64-f slice.
    int cmb = f0 >> 6;
    int b = cmb / 6;
    const float* a = (b == 0) ? pa0 : (b == 1) ? pa1 : pa2;
    int r = threadIdx.x >> 2;
    int part = (threadIdx.x & 3) * 16;
    float dl = 0.f, dr = 0.f;
#pragma unroll
    for (int k = 0; k < 16; ++k) {
      float gv = (float)t[r][part + k];
      dl += gv * a[part + k];
      dr += gv * a[64 + part + k];
    }
    dl += __shfl_xor(dl, 1, 64); dr += __shfl_xor(dr, 1, 64);
    dl += __shfl_xor(dl, 2, 64); dr += __shfl_xor(dr, 2, 64);
    if ((threadIdx.x & 3) == 0) {
      int o = cmb * N_NODES + j0 + r;
      elp[o] = fexp2(dl * LOG2E);
      eln[o] = fexp2(0.2f * dl * LOG2E);
      erp[o] = fexp2(dr * LOG2E);
      ern[o] = fexp2(0.2f * dr * LOG2E);
    }
  }
}

// ---------------------------------------------------------------- head projections (layer2 only) -> exp-factor arrays
template<int NCPB, int NH>
__global__ __launch_bounds__(256) void head_proj_kernel(
    const bf16* __restrict__ g, int ldg,
    const float* __restrict__ a0, const float* __restrict__ a1, const float* __restrict__ a2,
    float* __restrict__ elp, float* __restrict__ eln,
    float* __restrict__ erp, float* __restrict__ ern) {
  int c = blockIdx.y;
  int i = blockIdx.x * 16 + (threadIdx.x >> 4);
  int b = c / NCPB;
  const float* a = (b == 0) ? a0 : (b == 1) ? a1 : a2;
  int f0 = (threadIdx.x & 15) * (NH / 16);
  const bf16* gr = g + (size_t)i * ldg + c * NH + f0;
  float accl = 0.f, accr = 0.f;
#pragma unroll
  for (int k = 0; k < NH / 16; k += 4) {
    bf16x4 v = *(const bf16x4*)&gr[k];
#pragma unroll
    for (int e = 0; e < 4; ++e) {
      float gv = (float)v[e];
      accl += gv * a[f0 + k + e];
      accr += gv * a[NH + f0 + k + e];
    }
  }
#pragma unroll
  for (int m = 1; m < 16; m <<= 1) {
    accl += __shfl_xor(accl, m, 64);
    accr += __shfl_xor(accr, m, 64);
  }
  if ((threadIdx.x & 15) == 0) {
    int o = c * N_NODES + i;
    elp[o] = fexp2(accl * LOG2E);
    eln[o] = fexp2(0.2f * accl * LOG2E);
    erp[o] = fexp2(accr * LOG2E);
    ern[o] = fexp2(0.2f * accr * LOG2E);
  }
}

// ---------------------------------------------------------------- GEMM 64x64 tile, single-barrier LDS double-buffer
template<bool BIAS, bool LEAKY, bool RES, bool F32OUT>
__global__ __launch_bounds__(256) void gemm64_kernel(
    const bf16* __restrict__ A, int lda, int aZoff,
    const bf16* __restrict__ B0, const bf16* __restrict__ B1, const bf16* __restrict__ B2,
    int ldb, void* __restrict__ Cout, int ldc, int cZoff, int K,
    const float* __restrict__ bias, const float* __restrict__ res) {
  __shared__ bf16 As[2 * 64 * 64];
  __shared__ bf16 Bs[2 * 64 * 64];
  int z = blockIdx.z;
  const bf16* Ab = A + (size_t)z * aZoff;
  const bf16* Bb = (z == 0) ? B0 : (z == 1) ? B1 : B2;
  int m0 = blockIdx.x * 64, n0 = blockIdx.y * 64;
  int tid = threadIdx.x;
  int lane = tid & 63, wave = tid >> 6;
  int wm = wave >> 1, wn = wave & 1;
  int l15 = lane & 15, lk = lane >> 4;
  int r0 = tid >> 3, p0 = tid & 7, q0 = p0 ^ (r0 & 7);
  int r1 = (256 + tid) >> 3, p1 = tid & 7, q1 = p1 ^ (r1 & 7);
  bf16x8 ra0, ra1, rb0, rb1;
  auto gload = [&](int kt) {
    const bf16* ab = Ab + (size_t)kt * 64;
    const bf16* bb = Bb + (size_t)kt * 64;
    ra0 = *(const bf16x8*)&ab[(size_t)(m0 + r0) * lda + q0 * 8];
    ra1 = *(const bf16x8*)&ab[(size_t)(m0 + r1) * lda + q1 * 8];
    rb0 = *(const bf16x8*)&bb[(size_t)(n0 + r0) * ldb + q0 * 8];
    rb1 = *(const bf16x8*)&bb[(size_t)(n0 + r1) * ldb + q1 * 8];
  };
  auto sstore = [&](int buf) {
    bf16* as = As + buf * 4096;
    bf16* bs = Bs + buf * 4096;
    *(bf16x8*)&as[r0 * 64 + p0 * 8] = ra0;
    *(bf16x8*)&as[r1 * 64 + p1 * 8] = ra1;
    *(bf16x8*)&bs[r0 * 64 + p0 * 8] = rb0;
    *(bf16x8*)&bs[r1 * 64 + p1 * 8] = rb1;
  };
  f32x4 acc[2][2] = {};
  int nk = K >> 6;
  gload(0);
  sstore(0);
  __syncthreads();
  for (int kt = 0; kt < nk; ++kt) {
    bool more = (kt + 1) < nk;
    if (more) gload(kt + 1);
    const bf16* as = As + (kt & 1) * 4096;
    const bf16* bs = Bs + (kt & 1) * 4096;
#pragma unroll
    for (int s = 0; s < 2; ++s) {
      bf16x8 af[2], bfr[2];
      int u = s * 4 + lk;
#pragma unroll
      for (int mi = 0; mi < 2; ++mi) {
        int r = wm * 32 + mi * 16 + l15;
        af[mi] = *(const bf16x8*)&as[r * 64 + (u ^ (r & 7)) * 8];
      }
#pragma unroll
      for (int ni = 0; ni < 2; ++ni) {
        int r = wn * 32 + ni * 16 + l15;
        bfr[ni] = *(const bf16x8*)&bs[r * 64 + (u ^ (r & 7)) * 8];
      }
#pragma unroll
      for (int mi = 0; mi < 2; ++mi)
#pragma unroll
        for (int ni = 0; ni < 2; ++ni)
          acc[mi][ni] = __builtin_amdgcn_mfma_f32_16x16x32_bf16(af[mi], bfr[ni], acc[mi][ni], 0, 0, 0);
    }
    if (more) sstore((kt + 1) & 1);
    __syncthreads();
  }
#pragma unroll
  for (int mi = 0; mi < 2; ++mi)
#pragma unroll
    for (int ni = 0; ni < 2; ++ni)
#pragma unroll
      for (int r = 0; r < 4; ++r) {
        int i = m0 + wm * 32 + mi * 16 + lk * 4 + r;
        int col = z * cZoff + n0 + wn * 32 + ni * 16 + l15;
        float v = acc[mi][ni][r];
        if (BIAS) v += bias[col];
        if (LEAKY) v = (v >= 0.f) ? v : 0.01f * v;
        if (RES) v += res[(size_t)i * ldc + col];
        if (F32OUT) ((float*)Cout)[(size_t)i * ldc + col] = v;
        else        ((bf16*)Cout)[(size_t)i * ldc + col] = (bf16)v;
      }
}

// ---------------------------------------------------------------- attention: LDS-staged 2-phase pipeline
template<bool L1>
__global__ __launch_bounds__(256, 2) void att_kernel(
    const bf16* __restrict__ gP,
    const float* __restrict__ elpA, const float* __restrict__ elnA,
    const float* __restrict__ erpA, const float* __restrict__ ernA,
    const unsigned char* __restrict__ adjT,
    const int* __restrict__ dnum, const int* __restrict__ snum,
    float* __restrict__ accP, float* __restrict__ lP) {
  constexpr int C = L1 ? C1 : C2;
  int c = blockIdx.y;
  int b = L1 ? (c / 6) : (c >> 2);
  int colbase = L1 ? c * 64 : (b * 256 + (c & 3) * 64);
  int sidx = L1 ? c : b;
  int q = blockIdx.z;
  int Qb = (b == 0) ? QS : 1;
  if (q >= Qb) return;
  int dn = dnum[0], sn = snum[0];
  int bb1 = N_NODES - sn - dn, bb2 = N_NODES - dn;
  int jlo = (b == 0) ? 0 : (b == 1) ? bb1 : bb2;
  int jhi = (b == 0) ? bb1 : (b == 1) ? bb2 : N_NODES;
  int len = jhi - jlo;
  int wlo = bnd32(jlo, jhi, len, q, Qb);
  int whi = bnd32(jlo, jhi, len, q + 1, Qb);
  if (wlo >= whi) return;

  __shared__ bf16  sgP[2][8][64 * 8];   // [buf][octet][col][8]
  __shared__ float serp[2][64];
  __shared__ float sern[2][64];

  int wave = threadIdx.x >> 6, lane = threadIdx.x & 63;
  int l15 = lane & 15, lk = lane >> 4;
  int row0 = blockIdx.x * 256 + wave * 64;   // this wave's 64 rows
  float elp[4], eln[4];
#pragma unroll
  for (int rg = 0; rg < 4; ++rg) {
    int ip = row0 + rg * 16 + l15;
    elp[rg] = elpA[sidx * N_NODES + ip];
    eln[rg] = elnA[sidx * N_NODES + ip];
  }
  const float* erpB = erpA + sidx * N_NODES;
  const float* ernB = ernA + sidx * N_NODES;
  const bf16* gPcol = gP + (size_t)colbase * 8;
  bf16x8 ones;
#pragma unroll
  for (int e = 0; e < 8; ++e) ones[e] = (bf16)1.0f;
  f32x4 acc[4][4] = {};
  f32x4 accl[4] = {};

  auto stage = [&](int buf, int cb) {
    int mo0 = cb >> 3;
#pragma unroll
    for (int k = 0; k < 2; ++k) {
      int ml = wave * 2 + k;
      if ((mo0 + ml) * 8 < whi)
        gload_lds16(gPcol + ((size_t)(mo0 + ml) * C + lane) * 8, &sgP[buf][ml][0]);
    }
    if (wave == 0) gload_lds4(erpB + cb + lane, &serp[buf][0]);
    if (wave == 1) gload_lds4(ernB + cb + lane, &sern[buf][0]);
  };

  int buf = 0;
  stage(0, wlo);
  asm volatile("s_waitcnt vmcnt(0)" ::: "memory");
  __syncthreads();
  for (int cb = wlo; cb < whi; cb += 64) {
    int nb = cb + 64;
    if (nb < whi) stage(buf ^ 1, nb);    // in flight during compute below
#pragma unroll
    for (int h = 0; h < 2; ++h) {
      int jt = cb + h * 32;
      if (jt >= whi) break;
      int lj = h * 32 + lk * 8;          // lane's local j-octet offset
      int oct = h * 4 + lk;
      int mo = (jt >> 3) + lk;
      int j0o = mo << 3;
      int lo = min(max(jlo - j0o, 0), 8);
      int hi = min(max(jhi - j0o, 0), 8);
      unsigned int rb_ = ((1u << hi) - 1u) & ~((1u << lo) - 1u);
      f32x4 pv0 = *(const f32x4*)&serp[buf][lj];
      f32x4 pv1 = *(const f32x4*)&serp[buf][lj + 4];
      f32x4 nv0 = *(const f32x4*)&sern[buf][lj];
      f32x4 nv1 = *(const f32x4*)&sern[buf][lj + 4];
      bf16x8 bf0 = *(const bf16x8*)&sgP[buf][oct][(0 * 16 + l15) * 8];
      bf16x8 bf1 = *(const bf16x8*)&sgP[buf][oct][(1 * 16 + l15) * 8];
      bf16x8 bf2 = *(const bf16x8*)&sgP[buf][oct][(2 * 16 + l15) * 8];
      bf16x8 bf3 = *(const bf16x8*)&sgP[buf][oct][(3 * 16 + l15) * 8];
      const unsigned char* mT = adjT + (size_t)mo * N_NODES + row0;
#pragma unroll
      for (int rg = 0; rg < 4; ++rg) {
        unsigned int mb = mT[rg * 16 + l15] & rb_;
        bf16x8 a8;
#pragma unroll
        for (int e = 0; e < 8; ++e) {
          float pvv = (e < 4) ? pv0[e & 3] : pv1[e & 3];
          float nvv = (e < 4) ? nv0[e & 3] : nv1[e & 3];
          float z = elp[rg] * pvv;
          float w = eln[rg] * nvv;
          float p = (z >= 1.f) ? z : w;
          p = ((mb >> e) & 1u) ? p : 0.f;
          a8[e] = (bf16)p;
        }
        acc[rg][0] = __builtin_amdgcn_mfma_f32_16x16x32_bf16(a8, bf0, acc[rg][0], 0, 0, 0);
        acc[rg][1] = __builtin_amdgcn_mfma_f32_16x16x32_bf16(a8, bf1, acc[rg][1], 0, 0, 0);
        acc[rg][2] = __builtin_amdgcn_mfma_f32_16x16x32_bf16(a8, bf2, acc[rg][2], 0, 0, 0);
        acc[rg][3] = __builtin_amdgcn_mfma_f32_16x16x32_bf16(a8, bf3, acc[rg][3], 0, 0, 0);
        accl[rg]   = __builtin_amdgcn_mfma_f32_16x16x32_bf16(a8, ones, accl[rg], 0, 0, 0);
      }
    }
    asm volatile("s_waitcnt vmcnt(0)" ::: "memory");
    __syncthreads();                      // next buffer fully staged; safe to swap
    buf ^= 1;
  }

  int slot = (b == 0) ? (c * QS + q) : (L1 ? (36 + (c - 6)) : (24 + (c - 4)));
  float* ap = accP + ((size_t)slot * N_NODES + row0) * 64;
#pragma unroll
  for (int rg = 0; rg < 4; ++rg)
#pragma unroll
    for (int nf = 0; nf < 4; ++nf)
#pragma unroll
      for (int r = 0; r < 4; ++r)
        ap[(rg * 16 + lk * 4 + r) * 64 + nf * 16 + l15] = acc[rg][nf][r];
  if (l15 == 0) {
#pragma unroll
    for (int rg = 0; rg < 4; ++rg)
#pragma unroll
      for (int r = 0; r < 4; ++r)
        lP[(size_t)slot * N_NODES + row0 + rg * 16 + lk * 4 + r] = accl[rg][r];
  }
}

// ---------------------------------------------------------------- finalize layer 1: sum slices, /l (or gmean), ELU
__global__ __launch_bounds__(256) void fin1_kernel(
    const float* __restrict__ accP, const float* __restrict__ lP,
    const float* __restrict__ gm, const int* __restrict__ dnum, const int* __restrict__ snum,
    bf16* __restrict__ out1) {
  int t = blockIdx.x * 256 + threadIdx.x;
  int i = t / (C1 / 8), f0 = (t - i * (C1 / 8)) * 8;
  int c = f0 >> 6;
  int b = c / 6;
  int dn = dnum[0], sn = snum[0];
  int bb1 = N_NODES - sn - dn, bb2 = N_NODES - dn;
  int jlo = (b == 0) ? 0 : (b == 1) ? bb1 : bb2;
  int jhi = (b == 0) ? bb1 : (b == 1) ? bb2 : N_NODES;
  int len = jhi - jlo;
  int Qb = (b == 0) ? QS : 1;
  float l = 0.f;
  float a[8] = {0.f,0.f,0.f,0.f,0.f,0.f,0.f,0.f};
  if (len > 0) {
    for (int q = 0; q < Qb; ++q) {
      if (bnd32(jlo, jhi, len, q, Qb) >= bnd32(jlo, jhi, len, q + 1, Qb)) continue;
      int slot = (b == 0) ? (c * QS + q) : (36 + (c - 6));
      l += lP[(size_t)slot * N_NODES + i];
      const float* ap = &accP[((size_t)slot * N_NODES + i) * 64 + (f0 & 63)];
      f32x4 v0 = *(const f32x4*)ap, v1 = *(const f32x4*)(ap + 4);
#pragma unroll
      for (int e = 0; e < 4; ++e) { a[e] += v0[e]; a[e + 4] += v1[e]; }
    }
  }
  float inv = (l > 0.f) ? 1.f / l : 0.f;
  bf16x8 o;
#pragma unroll
  for (int e = 0; e < 8; ++e) {
    float v = (l > 0.f) ? a[e] * inv : gm[f0 + e];
    v = (v > 0.f) ? v : (__expf(v) - 1.f);   // ELU
    o[e] = (bf16)v;
  }
  *(bf16x8*)&out1[(size_t)i * C1 + f0] = o;
}

// ---------------------------------------------------------------- finalize layer 2: sum slices, /l (or gmean), +residual -> fused
__global__ __launch_bounds__(256) void fin2_kernel(
    const float* __restrict__ accP, const float* __restrict__ lP,
    const float* __restrict__ gm, const float* __restrict__ feat,
    const int* __restrict__ dnum, const int* __restrict__ snum,
    bf16* __restrict__ fused) {
  int t = blockIdx.x * 256 + threadIdx.x;
  int i = t / (C2 / 8), f0 = (t - i * (C2 / 8)) * 8;
  int b = f0 >> 8;
  int fi = f0 & 255;
  int fc = (f0 >> 6) & 3;
  int c = b * 4 + fc;
  int dn = dnum[0], sn = snum[0];
  int bb1 = N_NODES - sn - dn, bb2 = N_NODES - dn;
  int jlo = (b == 0) ? 0 : (b == 1) ? bb1 : bb2;
  int jhi = (b == 0) ? bb1 : (b == 1) ? bb2 : N_NODES;
  int len = jhi - jlo;
  int Qb = (b == 0) ? QS : 1;
  float l = 0.f;
  float a[8] = {0.f,0.f,0.f,0.f,0.f,0.f,0.f,0.f};
  if (len > 0) {
    for (int q = 0; q < Qb; ++q) {
      if (bnd32(jlo, jhi, len, q, Qb) >= bnd32(jlo, jhi, len, q + 1, Qb)) continue;
      int slot = (b == 0) ? (c * QS + q) : (24 + (c - 4));
      l += lP[(size_t)slot * N_NODES + i];
      const float* ap = &accP[((size_t)slot * N_NODES + i) * 64 + (f0 & 63)];
      f32x4 v0 = *(const f32x4*)ap, v1 = *(const f32x4*)(ap + 4);
#pragma unroll
      for (int e = 0; e < 4; ++e) { a[e] += v0[e]; a[e + 4] += v1[e]; }
    }
  }
  float inv = (l > 0.f) ? 1.f / l : 0.f;
  bf16x8 o;
#pragma unroll
  for (int e = 0; e < 8; ++e) {
    float v = (l > 0.f) ? a[e] * inv : gm[f0 + e];
    v += feat[(size_t)i * D_IN + fi + e];
    o[e] = (bf16)v;
  }
  *(bf16x8*)&fused[(size_t)i * C2 + (2 - b) * D_IN + fi] = o;
}

// ---------------------------------------------------------------- launch
extern "C" void kernel_launch(void* const* d_in, const int* in_sizes, int n_in,
                              void* d_out, int out_size, void* d_ws, size_t ws_size,
                              hipStream_t stream) {
  (void)in_sizes; (void)n_in; (void)out_size; (void)ws_size;
  const float* feature = (const float*)d_in[0];
  const int*   adj     = (const int*)d_in[1];
  const int*   dnum    = (const int*)d_in[2];
  const int*   snum    = (const int*)d_in[3];
  const float* W1s = (const float*)d_in[4];  const float* a1s = (const float*)d_in[5];
  const float* W2s = (const float*)d_in[6];  const float* a2s = (const float*)d_in[7];
  const float* W1e = (const float*)d_in[8];  const float* a1e = (const float*)d_in[9];
  const float* W2e = (const float*)d_in[10]; const float* a2e = (const float*)d_in[11];
  const float* W1d = (const float*)d_in[12]; const float* a1d = (const float*)d_in[13];
  const float* W2d = (const float*)d_in[14]; const float* a2d = (const float*)d_in[15];
  const float* fW  = (const float*)d_in[16]; const float* fB  = (const float*)d_in[17];
  const float* w0  = (const float*)d_in[18]; const float* b0  = (const float*)d_in[19];
  const float* w1  = (const float*)d_in[20]; const float* b1  = (const float*)d_in[21];
  const float* w2  = (const float*)d_in[22]; const float* b2  = (const float*)d_in[23];

  char* ws = (char*)d_ws;
  size_t off = 0;
  auto alloc = [&](size_t bytes) { void* p = ws + off; off += (bytes + 255) & ~(size_t)255; return p; };

  unsigned char* adjT = (unsigned char*)alloc((size_t)384 * N_NODES);  // [mo][row], 1.125 MB
  bf16* fbf   = (bf16*)alloc((size_t)N_NODES * D_IN * 2);
  bf16* w1b0  = (bf16*)alloc(HIDDEN * D_IN * 2);
  bf16* w1b1  = (bf16*)alloc(HIDDEN * D_IN * 2);
  bf16* w1b2  = (bf16*)alloc(HIDDEN * D_IN * 2);
  bf16* w2b0  = (bf16*)alloc(D_IN * HIDDEN * 2);
  bf16* w2b1  = (bf16*)alloc(D_IN * HIDDEN * 2);
  bf16* w2b2  = (bf16*)alloc(D_IN * HIDDEN * 2);
  bf16* wfusb = (bf16*)alloc(D_IN * C2 * 2);
  bf16* wf0b  = (bf16*)alloc(HIDDEN * D_IN * 2);
  bf16* wf1b  = (bf16*)alloc(HIDDEN * HIDDEN * 2);
  bf16* wf2b  = (bf16*)alloc(D_IN * HIDDEN * 2);
  bf16* g1    = (bf16*)alloc((size_t)N_NODES * C1 * 2);
  bf16* gP1   = (bf16*)alloc((size_t)N_NODES * C1 * 2);
  bf16* out1  = (bf16*)alloc((size_t)N_NODES * C1 * 2);
  bf16* g2    = (bf16*)alloc((size_t)N_NODES * C2 * 2);
  bf16* gP2   = (bf16*)alloc((size_t)N_NODES * C2 * 2);
  bf16* fusedB= (bf16*)alloc((size_t)N_NODES * C2 * 2);
  bf16* h0    = (bf16*)alloc((size_t)N_NODES * D_IN * 2);
  bf16* h1    = (bf16*)alloc((size_t)N_NODES * HIDDEN * 2);
  bf16* h2    = (bf16*)alloc((size_t)N_NODES * HIDDEN * 2);
  float* elp1 = (float*)alloc(18 * N_NODES * 4);
  float* eln1 = (float*)alloc(18 * N_NODES * 4);
  float* erp1 = (float*)alloc(18 * N_NODES * 4);
  float* ern1 = (float*)alloc(18 * N_NODES * 4);
  float* elp2 = (float*)alloc(3 * N_NODES * 4);
  float* eln2 = (float*)alloc(3 * N_NODES * 4);
  float* erp2 = (float*)alloc(3 * N_NODES * 4);
  float* ern2 = (float*)alloc(3 * N_NODES * 4);
  float* accU = (float*)alloc((size_t)48 * N_NODES * 64 * 4);  // 37.7 MB
  float* lU   = (float*)alloc((size_t)48 * N_NODES * 4);
  size_t zoff = off;
  float* gm1  = (float*)alloc(C1 * 4);
  float* gm2  = (float*)alloc(C2 * 4);
  size_t zbytes = off - zoff;

  hipMemsetAsync(ws + zoff, 0, zbytes, stream);

  // 1) casts + adj transpose (merged)
  CastArgs ca;
  {
    const float* srcs[11] = { feature, W1s, W1e, W1d, W2s, W2e, W2d, fW, w0, w1, w2 };
    bf16* dsts[11] = { fbf, w1b0, w1b1, w1b2, w2b0, w2b1, w2b2, wfusb, wf0b, wf1b, wf2b };
    int counts[11] = { N_NODES*D_IN, HIDDEN*D_IN, HIDDEN*D_IN, HIDDEN*D_IN,
                       D_IN*HIDDEN, D_IN*HIDDEN, D_IN*HIDDEN, D_IN*C2,
                       HIDDEN*D_IN, HIDDEN*HIDDEN, D_IN*HIDDEN };
    int cum = 0;
    for (int k = 0; k < 11; ++k) { ca.src[k] = srcs[k]; ca.dst[k] = dsts[k]; ca.cum4[k] = cum; cum += counts[k] / 4; }
    ca.cum4[11] = cum;
    ca.castN = cum / 256;
    prep_kernel<<<ca.castN + 288, 256, 0, stream>>>(ca, adj, adjT);
  }
  // 2) g1 = f @ W1^T (3 branches via z)
  gemm64_kernel<false,false,false,false><<<dim3(48,6,3), 256, 0, stream>>>(
      fbf, D_IN, 0, w1b0, w1b1, w1b2, D_IN, g1, C1, HIDDEN, D_IN, nullptr, nullptr);
  // 3) pack g1 -> gP1 (+colmean +layer1 head-proj fold)
  pack_kernel<C1,true><<<dim3(48,18), 256, 0, stream>>>(g1, gP1, gm1, a1s, a1e, a1d, elp1, eln1, erp1, ern1);
  // 4) attention 1 partials (LDS-staged 2-phase)
  att_kernel<true><<<dim3(12, 18, QS), 256, 0, stream>>>(gP1, elp1, eln1, erp1, ern1, adjT, dnum, snum, accU, lU);
  // 4b) finalize 1 (+ELU)
  fin1_kernel<<<N_NODES * (C1 / 8) / 256, 256, 0, stream>>>(accU, lU, gm1, dnum, snum, out1);
  // 5) g2 = out1 @ W2^T per branch
  gemm64_kernel<false,false,false,false><<<dim3(48,4,3), 256, 0, stream>>>(
      out1, C1, HIDDEN, w2b0, w2b1, w2b2, HIDDEN, g2, C2, D_IN, HIDDEN, nullptr, nullptr);
  // 6) pack g2 -> gP2 (+colmean)
  pack_kernel<C2,false><<<dim3(48,12), 256, 0, stream>>>(g2, gP2, gm2,
      nullptr, nullptr, nullptr, nullptr, nullptr, nullptr, nullptr);
  // 7) exp factors layer2
  head_proj_kernel<1, D_IN><<<dim3(192,3), 256, 0, stream>>>(g2, C2, a2s, a2e, a2d, elp2, eln2, erp2, ern2);
  // 8) attention 2 partials
  att_kernel<false><<<dim3(12, 12, QS), 256, 0, stream>>>(gP2, elp2, eln2, erp2, ern2, adjT, dnum, snum, accU, lU);
  // 8b) finalize 2 (+residual, writes fused [doc,sect,sent])
  fin2_kernel<<<N_NODES * (C2 / 8) / 256, 256, 0, stream>>>(accU, lU, gm2, feature, dnum, snum, fusedB);
  // 9) fusion: h0 = leaky(fused @ fW^T + fB)
  gemm64_kernel<true,true,false,false><<<dim3(48,4,1), 256, 0, stream>>>(
      fusedB, C2, 0, wfusb, wfusb, wfusb, C2, h0, D_IN, 0, C2, fB, nullptr);
  // 10) ffn0: h1 = leaky(h0 @ w0^T + b0)
  gemm64_kernel<true,true,false,false><<<dim3(48,6,1), 256, 0, stream>>>(
      h0, D_IN, 0, wf0b, wf0b, wf0b, D_IN, h1, HIDDEN, 0, D_IN, b0, nullptr);
  // 11) ffn1: h2 = leaky(h1 @ w1^T + b1)
  gemm64_kernel<true,true,false,false><<<dim3(48,6,1), 256, 0, stream>>>(
      h1, HIDDEN, 0, wf1b, wf1b, wf1b, HIDDEN, h2, HIDDEN, 0, HIDDEN, b1, nullptr);
  // 12) ffn2: out = leaky(h2 @ w2^T + b2) + f   (fp32 out)
  gemm64_kernel<true,true,true,true><<<dim3(48,4,1), 256, 0, stream>>>(
      h2, HIDDEN, 0, wf2b, wf2b, wf2b, HIDDEN, d_out, D_IN, 0, HIDDEN, b2, feature);
}

// Round 11
// 265.502 us; speedup vs baseline: 1.1599x; 1.0268x over previous
//
#include <hip/hip_runtime.h>
#include <stdint.h>

#define N_NODES 3072
#define D_IN    256
#define HIDDEN  384
#define HEADS   6
#define NH1     64
#define C1      1152   // 3*HIDDEN
#define C2      768    // 3*D_IN
#define QS      8      // j-splits for the sent branch (sect/doc get 1)
#define LOG2E   1.4426950408889634f

typedef __bf16 bf16;
typedef __bf16 bf16x8 __attribute__((ext_vector_type(8)));
typedef __bf16 bf16x4 __attribute__((ext_vector_type(4)));
typedef float  f32x4  __attribute__((ext_vector_type(4)));

typedef __attribute__((address_space(1))) const unsigned int as1_u32;
typedef __attribute__((address_space(3))) unsigned int as3_u32;

__device__ __forceinline__ void gload_lds16(const void* g, void* l) {
  __builtin_amdgcn_global_load_lds((as1_u32*)g, (as3_u32*)l, 16, 0, 0);
}
__device__ __forceinline__ void gload_lds4(const void* g, void* l) {
  __builtin_amdgcn_global_load_lds((as1_u32*)g, (as3_u32*)l, 4, 0, 0);
}

__device__ __forceinline__ void atomAddF(float* p, float v) {
  __hip_atomic_fetch_add(p, v, __ATOMIC_RELAXED, __HIP_MEMORY_SCOPE_AGENT);
}
__device__ __forceinline__ float fexp2(float x) {   // D = 2^S0
  float r; asm("v_exp_f32 %0, %1" : "=v"(r) : "v"(x)); return r;
}
// 32-aligned chunk boundary: q in [0,Qb]; B(0) floors jlo, B(Qb) ceils jhi.
__device__ __forceinline__ int bnd32(int jlo, int jhi, int len, int q, int Qb) {
  return (q >= Qb) ? ((jhi + 31) & ~31) : ((jlo + (len * q) / Qb) & ~31);
}

// ---------------------------------------------------------------- merged: cast fp32->bf16 + adj -> transposed byte mask adjT[mo][row]
struct CastArgs {
  const float* src[11];
  bf16*        dst[11];
  int          cum4[12];
  int          castN;     // # cast blocks; blocks beyond do adj transpose tiles
};

__global__ __launch_bounds__(256) void prep_kernel(CastArgs A,
                                                   const int* __restrict__ adj,
                                                   unsigned char* __restrict__ adjT) {
  if ((int)blockIdx.x < A.castN) {
    int g = blockIdx.x * 256 + threadIdx.x;
    int j = 0;
#pragma unroll
    for (int k = 1; k < 11; ++k) j += (g >= A.cum4[k]);
    int e = (g - A.cum4[j]) * 4;
    float4 v = *(const float4*)(A.src[j] + e);
    bf16x4 o = { (bf16)v.x, (bf16)v.y, (bf16)v.z, (bf16)v.w };
    *(bf16x4*)(A.dst[j] + e) = o;
    return;
  }
  // adj transpose: 288 blocks = (48 row-blocks x 64 rows) x (6 mo-blocks x 64 mo)
  int blk = blockIdx.x - A.castN;
  int rb = blk / 6, jb = blk - rb * 6;
  int row0 = rb * 64, mo0 = jb * 64;
  __shared__ unsigned char tile[64][68];   // pad 68 -> bank-free
#pragma unroll
  for (int s = 0; s < 16; ++s) {
    int bI = s * 256 + threadIdx.x;
    int row = bI >> 6, mo = bI & 63;
    const int4* p = (const int4*)(adj + (size_t)(row0 + row) * N_NODES + (size_t)(mo0 + mo) * 8);
    int4 v0 = p[0], v1 = p[1];
    unsigned int by = (unsigned)(v0.x != 0)        | ((unsigned)(v0.y != 0) << 1)
                    | ((unsigned)(v0.z != 0) << 2) | ((unsigned)(v0.w != 0) << 3)
                    | ((unsigned)(v1.x != 0) << 4) | ((unsigned)(v1.y != 0) << 5)
                    | ((unsigned)(v1.z != 0) << 6) | ((unsigned)(v1.w != 0) << 7);
    tile[mo][row] = (unsigned char)by;
  }
  __syncthreads();
  unsigned int* gu = (unsigned int*)adjT;
#pragma unroll
  for (int k = 0; k < 4; ++k) {
    int idx = k * 256 + threadIdx.x;
    int mo = idx >> 4, rw = idx & 15;
    unsigned int w = *(const unsigned int*)&tile[mo][rw * 4];
    gu[(size_t)(mo0 + mo) * (N_NODES / 4) + (row0 >> 2) + rw] = w;
  }
}

// ---------------------------------------------------------------- pack g[j][f] -> gP[j/8][f][8] + colmeans (+ layer1 head-proj fold)
template<int C, bool FOLD>
__global__ __launch_bounds__(256) void pack_kernel(const bf16* __restrict__ src,
                                                   bf16* __restrict__ dst,
                                                   float* __restrict__ gm,
                                                   const float* __restrict__ pa0,
                                                   const float* __restrict__ pa1,
                                                   const float* __restrict__ pa2,
                                                   float* __restrict__ elp,
                                                   float* __restrict__ eln,
                                                   float* __restrict__ erp,
                                                   float* __restrict__ ern) {
  __shared__ bf16 t[64][72];
  int j0 = blockIdx.x * 64, f0 = blockIdx.y * 64;
  int rr = threadIdx.x >> 4;
  int cc = (threadIdx.x & 15) * 4;
#pragma unroll
  for (int p = 0; p < 4; ++p) {
    int r = p * 16 + rr;
    *(bf16x4*)&t[r][cc] = *(const bf16x4*)&src[(size_t)(j0 + r) * C + f0 + cc];
  }
  __syncthreads();
  int f = threadIdx.x & 63, g = threadIdx.x >> 6;
#pragma unroll
  for (int q = 0; q < 2; ++q) {
    int p = g * 2 + q;
    bf16x8 v = { t[p*8+0][f], t[p*8+1][f], t[p*8+2][f], t[p*8+3][f],
                 t[p*8+4][f], t[p*8+5][f], t[p*8+6][f], t[p*8+7][f] };
    *(bf16x8*)&dst[ ((size_t)((j0 >> 3) + p) * C + f0 + f) * 8 ] = v;
  }
  float s = 0.f;
#pragma unroll
  for (int k = 0; k < 16; ++k) s += (float)t[g * 16 + k][f];
  atomAddF(&gm[f0 + f], s * (1.0f / N_NODES));
  if constexpr (FOLD) {
    int cmb = f0 >> 6;
    int b = cmb / 6;
    const float* a = (b == 0) ? pa0 : (b == 1) ? pa1 : pa2;
    int r = threadIdx.x >> 2;
    int part = (threadIdx.x & 3) * 16;
    float dl = 0.f, dr = 0.f;
#pragma unroll
    for (int k = 0; k < 16; ++k) {
      float gv = (float)t[r][part + k];
      dl += gv * a[part + k];
      dr += gv * a[64 + part + k];
    }
    dl += __shfl_xor(dl, 1, 64); dr += __shfl_xor(dr, 1, 64);
    dl += __shfl_xor(dl, 2, 64); dr += __shfl_xor(dr, 2, 64);
    if ((threadIdx.x & 3) == 0) {
      int o = cmb * N_NODES + j0 + r;
      elp[o] = fexp2(dl * LOG2E);
      eln[o] = fexp2(0.2f * dl * LOG2E);
      erp[o] = fexp2(dr * LOG2E);
      ern[o] = fexp2(0.2f * dr * LOG2E);
    }
  }
}

// ---------------------------------------------------------------- merged: pack2 + layer2 head-proj (1D grid, block-role split)
__global__ __launch_bounds__(256) void pack2_proj_kernel(
    const bf16* __restrict__ g2, bf16* __restrict__ gP2, float* __restrict__ gm2,
    const float* __restrict__ a0, const float* __restrict__ a1, const float* __restrict__ a2,
    float* __restrict__ elp, float* __restrict__ eln,
    float* __restrict__ erp, float* __restrict__ ern) {
  __shared__ bf16 t[64][72];
  if ((int)blockIdx.x < 576) {
    int j0 = (blockIdx.x % 48) * 64, f0 = (blockIdx.x / 48) * 64;
    int rr = threadIdx.x >> 4;
    int cc = (threadIdx.x & 15) * 4;
#pragma unroll
    for (int p = 0; p < 4; ++p) {
      int r = p * 16 + rr;
      *(bf16x4*)&t[r][cc] = *(const bf16x4*)&g2[(size_t)(j0 + r) * C2 + f0 + cc];
    }
    __syncthreads();
    int f = threadIdx.x & 63, g = threadIdx.x >> 6;
#pragma unroll
    for (int q = 0; q < 2; ++q) {
      int p = g * 2 + q;
      bf16x8 v = { t[p*8+0][f], t[p*8+1][f], t[p*8+2][f], t[p*8+3][f],
                   t[p*8+4][f], t[p*8+5][f], t[p*8+6][f], t[p*8+7][f] };
      *(bf16x8*)&gP2[ ((size_t)((j0 >> 3) + p) * C2 + f0 + f) * 8 ] = v;
    }
    float s = 0.f;
#pragma unroll
    for (int k = 0; k < 16; ++k) s += (float)t[g * 16 + k][f];
    atomAddF(&gm2[f0 + f], s * (1.0f / N_NODES));
    return;
  }
  // head-proj layer2: 576 blocks = 192 i-blocks x 3 combos
  int pb = blockIdx.x - 576;
  int c = pb / 192;
  int i = (pb - c * 192) * 16 + (threadIdx.x >> 4);
  const float* a = (c == 0) ? a0 : (c == 1) ? a1 : a2;
  int f0 = (threadIdx.x & 15) * 16;
  const bf16* gr = g2 + (size_t)i * C2 + c * D_IN + f0;
  float accl = 0.f, accr = 0.f;
#pragma unroll
  for (int k = 0; k < 16; k += 4) {
    bf16x4 v = *(const bf16x4*)&gr[k];
#pragma unroll
    for (int e = 0; e < 4; ++e) {
      float gv = (float)v[e];
      accl += gv * a[f0 + k + e];
      accr += gv * a[D_IN + f0 + k + e];
    }
  }
#pragma unroll
  for (int m = 1; m < 16; m <<= 1) {
    accl += __shfl_xor(accl, m, 64);
    accr += __shfl_xor(accr, m, 64);
  }
  if ((threadIdx.x & 15) == 0) {
    int o = c * N_NODES + i;
    elp[o] = fexp2(accl * LOG2E);
    eln[o] = fexp2(0.2f * accl * LOG2E);
    erp[o] = fexp2(accr * LOG2E);
    ern[o] = fexp2(0.2f * accr * LOG2E);
  }
}

// ---------------------------------------------------------------- GEMM 32x64 tile, single-barrier LDS double-buffer
// Half-height tiles double the grid -> 2-4x resident waves for the small-N chain.
template<bool BIAS, bool LEAKY, bool RES, bool F32OUT>
__global__ __launch_bounds__(256) void gemm32_kernel(
    const bf16* __restrict__ A, int lda, int aZoff,
    const bf16* __restrict__ B0, const bf16* __restrict__ B1, const bf16* __restrict__ B2,
    int ldb, void* __restrict__ Cout, int ldc, int cZoff, int K,
    const float* __restrict__ bias, const float* __restrict__ res) {
  __shared__ bf16 As[2 * 32 * 64];
  __shared__ bf16 Bs[2 * 64 * 64];
  int z = blockIdx.z;
  const bf16* Ab = A + (size_t)z * aZoff;
  const bf16* Bb = (z == 0) ? B0 : (z == 1) ? B1 : B2;
  int m0 = blockIdx.x * 32, n0 = blockIdx.y * 64;
  int tid = threadIdx.x;
  int lane = tid & 63, wave = tid >> 6;
  int wm = wave >> 1, wn = wave & 1;          // 16-row x 32-col quadrant per wave
  int l15 = lane & 15, lk = lane >> 4;
  int rA = tid >> 3, pA = tid & 7, qA = pA ^ (rA & 7);        // A: 1 octet/thread
  int rB0 = tid >> 3, rB1 = 32 + (tid >> 3), pB = tid & 7;    // B: 2 octets/thread
  int qB0 = pB ^ (rB0 & 7), qB1 = pB ^ (rB1 & 7);
  bf16x8 ra, rb0, rb1;
  auto gload = [&](int kt) {
    const bf16* ab = Ab + (size_t)kt * 64;
    const bf16* bb = Bb + (size_t)kt * 64;
    ra  = *(const bf16x8*)&ab[(size_t)(m0 + rA) * lda + qA * 8];
    rb0 = *(const bf16x8*)&bb[(size_t)(n0 + rB0) * ldb + qB0 * 8];
    rb1 = *(const bf16x8*)&bb[(size_t)(n0 + rB1) * ldb + qB1 * 8];
  };
  auto sstore = [&](int buf) {
    bf16* as = As + buf * 2048;
    bf16* bs = Bs + buf * 4096;
    *(bf16x8*)&as[rA * 64 + pA * 8] = ra;
    *(bf16x8*)&bs[rB0 * 64 + pB * 8] = rb0;
    *(bf16x8*)&bs[rB1 * 64 + pB * 8] = rb1;
  };
  f32x4 acc[2] = {};
  int nk = K >> 6;
  gload(0);
  sstore(0);
  __syncthreads();
  for (int kt = 0; kt < nk; ++kt) {
    bool more = (kt + 1) < nk;
    if (more) gload(kt + 1);
    const bf16* as = As + (kt & 1) * 2048;
    const bf16* bs = Bs + (kt & 1) * 4096;
#pragma unroll
    for (int s = 0; s < 2; ++s) {
      int u = s * 4 + lk;
      int rm = wm * 16 + l15;
      bf16x8 af = *(const bf16x8*)&as[rm * 64 + (u ^ (rm & 7)) * 8];
#pragma unroll
      for (int ni = 0; ni < 2; ++ni) {
        int rn = wn * 32 + ni * 16 + l15;
        bf16x8 bf = *(const bf16x8*)&bs[rn * 64 + (u ^ (rn & 7)) * 8];
        acc[ni] = __builtin_amdgcn_mfma_f32_16x16x32_bf16(af, bf, acc[ni], 0, 0, 0);
      }
    }
    if (more) sstore((kt + 1) & 1);
    __syncthreads();
  }
#pragma unroll
  for (int ni = 0; ni < 2; ++ni)
#pragma unroll
    for (int r = 0; r < 4; ++r) {
      int i = m0 + wm * 16 + lk * 4 + r;
      int col = z * cZoff + n0 + wn * 32 + ni * 16 + l15;
      float v = acc[ni][r];
      if (BIAS) v += bias[col];
      if (LEAKY) v = (v >= 0.f) ? v : 0.01f * v;
      if (RES) v += res[(size_t)i * ldc + col];
      if (F32OUT) ((float*)Cout)[(size_t)i * ldc + col] = v;
      else        ((bf16*)Cout)[(size_t)i * ldc + col] = (bf16)v;
    }
}

// ---------------------------------------------------------------- attention: LDS-staged 2-phase pipeline
template<bool L1>
__global__ __launch_bounds__(256, 2) void att_kernel(
    const bf16* __restrict__ gP,
    const float* __restrict__ elpA, const float* __restrict__ elnA,
    const float* __restrict__ erpA, const float* __restrict__ ernA,
    const unsigned char* __restrict__ adjT,
    const int* __restrict__ dnum, const int* __restrict__ snum,
    float* __restrict__ accP, float* __restrict__ lP) {
  constexpr int C = L1 ? C1 : C2;
  int c = blockIdx.y;
  int b = L1 ? (c / 6) : (c >> 2);
  int colbase = L1 ? c * 64 : (b * 256 + (c & 3) * 64);
  int sidx = L1 ? c : b;
  int q = blockIdx.z;
  int Qb = (b == 0) ? QS : 1;
  if (q >= Qb) return;
  int dn = dnum[0], sn = snum[0];
  int bb1 = N_NODES - sn - dn, bb2 = N_NODES - dn;
  int jlo = (b == 0) ? 0 : (b == 1) ? bb1 : bb2;
  int jhi = (b == 0) ? bb1 : (b == 1) ? bb2 : N_NODES;
  int len = jhi - jlo;
  int wlo = bnd32(jlo, jhi, len, q, Qb);
  int whi = bnd32(jlo, jhi, len, q + 1, Qb);
  if (wlo >= whi) return;

  __shared__ bf16  sgP[2][8][64 * 8];
  __shared__ float serp[2][64];
  __shared__ float sern[2][64];

  int wave = threadIdx.x >> 6, lane = threadIdx.x & 63;
  int l15 = lane & 15, lk = lane >> 4;
  int row0 = blockIdx.x * 256 + wave * 64;
  float elp[4], eln[4];
#pragma unroll
  for (int rg = 0; rg < 4; ++rg) {
    int ip = row0 + rg * 16 + l15;
    elp[rg] = elpA[sidx * N_NODES + ip];
    eln[rg] = elnA[sidx * N_NODES + ip];
  }
  const float* erpB = erpA + sidx * N_NODES;
  const float* ernB = ernA + sidx * N_NODES;
  const bf16* gPcol = gP + (size_t)colbase * 8;
  bf16x8 ones;
#pragma unroll
  for (int e = 0; e < 8; ++e) ones[e] = (bf16)1.0f;
  f32x4 acc[4][4] = {};
  f32x4 accl[4] = {};

  auto stage = [&](int buf, int cb) {
    int mo0 = cb >> 3;
#pragma unroll
    for (int k = 0; k < 2; ++k) {
      int ml = wave * 2 + k;
      if ((mo0 + ml) * 8 < whi)
        gload_lds16(gPcol + ((size_t)(mo0 + ml) * C + lane) * 8, &sgP[buf][ml][0]);
    }
    if (wave == 0) gload_lds4(erpB + cb + lane, &serp[buf][0]);
    if (wave == 1) gload_lds4(ernB + cb + lane, &sern[buf][0]);
  };

  int buf = 0;
  stage(0, wlo);
  asm volatile("s_waitcnt vmcnt(0)" ::: "memory");
  __syncthreads();
  for (int cb = wlo; cb < whi; cb += 64) {
    int nb = cb + 64;
    if (nb < whi) stage(buf ^ 1, nb);
#pragma unroll
    for (int h = 0; h < 2; ++h) {
      int jt = cb + h * 32;
      if (jt >= whi) break;
      int lj = h * 32 + lk * 8;
      int oct = h * 4 + lk;
      int mo = (jt >> 3) + lk;
      int j0o = mo << 3;
      int lo = min(max(jlo - j0o, 0), 8);
      int hi = min(max(jhi - j0o, 0), 8);
      unsigned int rb_ = ((1u << hi) - 1u) & ~((1u << lo) - 1u);
      f32x4 pv0 = *(const f32x4*)&serp[buf][lj];
      f32x4 pv1 = *(const f32x4*)&serp[buf][lj + 4];
      f32x4 nv0 = *(const f32x4*)&sern[buf][lj];
      f32x4 nv1 = *(const f32x4*)&sern[buf][lj + 4];
      bf16x8 bf0 = *(const bf16x8*)&sgP[buf][oct][(0 * 16 + l15) * 8];
      bf16x8 bf1 = *(const bf16x8*)&sgP[buf][oct][(1 * 16 + l15) * 8];
      bf16x8 bf2 = *(const bf16x8*)&sgP[buf][oct][(2 * 16 + l15) * 8];
      bf16x8 bf3 = *(const bf16x8*)&sgP[buf][oct][(3 * 16 + l15) * 8];
      const unsigned char* mT = adjT + (size_t)mo * N_NODES + row0;
#pragma unroll
      for (int rg = 0; rg < 4; ++rg) {
        unsigned int mb = mT[rg * 16 + l15] & rb_;
        bf16x8 a8;
#pragma unroll
        for (int e = 0; e < 8; ++e) {
          float pvv = (e < 4) ? pv0[e & 3] : pv1[e & 3];
          float nvv = (e < 4) ? nv0[e & 3] : nv1[e & 3];
          float z = elp[rg] * pvv;
          float w = eln[rg] * nvv;
          float p = (z >= 1.f) ? z : w;
          p = ((mb >> e) & 1u) ? p : 0.f;
          a8[e] = (bf16)p;
        }
        acc[rg][0] = __builtin_amdgcn_mfma_f32_16x16x32_bf16(a8, bf0, acc[rg][0], 0, 0, 0);
        acc[rg][1] = __builtin_amdgcn_mfma_f32_16x16x32_bf16(a8, bf1, acc[rg][1], 0, 0, 0);
        acc[rg][2] = __builtin_amdgcn_mfma_f32_16x16x32_bf16(a8, bf2, acc[rg][2], 0, 0, 0);
        acc[rg][3] = __builtin_amdgcn_mfma_f32_16x16x32_bf16(a8, bf3, acc[rg][3], 0, 0, 0);
        accl[rg]   = __builtin_amdgcn_mfma_f32_16x16x32_bf16(a8, ones, accl[rg], 0, 0, 0);
      }
    }
    asm volatile("s_waitcnt vmcnt(0)" ::: "memory");
    __syncthreads();
    buf ^= 1;
  }

  int slot = (b == 0) ? (c * QS + q) : (L1 ? (6 * QS + (c - 6)) : (4 * QS + (c - 4)));
  float* ap = accP + ((size_t)slot * N_NODES + row0) * 64;
#pragma unroll
  for (int rg = 0; rg < 4; ++rg)
#pragma unroll
    for (int nf = 0; nf < 4; ++nf)
#pragma unroll
      for (int r = 0; r < 4; ++r)
        ap[(rg * 16 + lk * 4 + r) * 64 + nf * 16 + l15] = acc[rg][nf][r];
  if (l15 == 0) {
#pragma unroll
    for (int rg = 0; rg < 4; ++rg)
#pragma unroll
      for (int r = 0; r < 4; ++r)
        lP[(size_t)slot * N_NODES + row0 + rg * 16 + lk * 4 + r] = accl[rg][r];
  }
}

// ---------------------------------------------------------------- finalize layer 1: sum slices, /l (or gmean), ELU
__global__ __launch_bounds__(256) void fin1_kernel(
    const float* __restrict__ accP, const float* __restrict__ lP,
    const float* __restrict__ gm, const int* __restrict__ dnum, const int* __restrict__ snum,
    bf16* __restrict__ out1) {
  int t = blockIdx.x * 256 + threadIdx.x;
  int i = t / (C1 / 8), f0 = (t - i * (C1 / 8)) * 8;
  int c = f0 >> 6;
  int b = c / 6;
  int dn = dnum[0], sn = snum[0];
  int bb1 = N_NODES - sn - dn, bb2 = N_NODES - dn;
  int jlo = (b == 0) ? 0 : (b == 1) ? bb1 : bb2;
  int jhi = (b == 0) ? bb1 : (b == 1) ? bb2 : N_NODES;
  int len = jhi - jlo;
  int Qb = (b == 0) ? QS : 1;
  float l = 0.f;
  float a[8] = {0.f,0.f,0.f,0.f,0.f,0.f,0.f,0.f};
  if (len > 0) {
    for (int q = 0; q < Qb; ++q) {
      if (bnd32(jlo, jhi, len, q, Qb) >= bnd32(jlo, jhi, len, q + 1, Qb)) continue;
      int slot = (b == 0) ? (c * QS + q) : (6 * QS + (c - 6));
      l += lP[(size_t)slot * N_NODES + i];
      const float* ap = &accP[((size_t)slot * N_NODES + i) * 64 + (f0 & 63)];
      f32x4 v0 = *(const f32x4*)ap, v1 = *(const f32x4*)(ap + 4);
#pragma unroll
      for (int e = 0; e < 4; ++e) { a[e] += v0[e]; a[e + 4] += v1[e]; }
    }
  }
  float inv = (l > 0.f) ? 1.f / l : 0.f;
  bf16x8 o;
#pragma unroll
  for (int e = 0; e < 8; ++e) {
    float v = (l > 0.f) ? a[e] * inv : gm[f0 + e];
    v = (v > 0.f) ? v : (__expf(v) - 1.f);   // ELU
    o[e] = (bf16)v;
  }
  *(bf16x8*)&out1[(size_t)i * C1 + f0] = o;
}

// ---------------------------------------------------------------- finalize layer 2: sum slices, /l (or gmean), +residual -> fused
__global__ __launch_bounds__(256) void fin2_kernel(
    const float* __restrict__ accP, const float* __restrict__ lP,
    const float* __restrict__ gm, const float* __restrict__ feat,
    const int* __restrict__ dnum, const int* __restrict__ snum,
    bf16* __restrict__ fused) {
  int t = blockIdx.x * 256 + threadIdx.x;
  int i = t / (C2 / 8), f0 = (t - i * (C2 / 8)) * 8;
  int b = f0 >> 8;
  int fi = f0 & 255;
  int fc = (f0 >> 6) & 3;
  int c = b * 4 + fc;
  int dn = dnum[0], sn = snum[0];
  int bb1 = N_NODES - sn - dn, bb2 = N_NODES - dn;
  int jlo = (b == 0) ? 0 : (b == 1) ? bb1 : bb2;
  int jhi = (b == 0) ? bb1 : (b == 1) ? bb2 : N_NODES;
  int len = jhi - jlo;
  int Qb = (b == 0) ? QS : 1;
  float l = 0.f;
  float a[8] = {0.f,0.f,0.f,0.f,0.f,0.f,0.f,0.f};
  if (len > 0) {
    for (int q = 0; q < Qb; ++q) {
      if (bnd32(jlo, jhi, len, q, Qb) >= bnd32(jlo, jhi, len, q + 1, Qb)) continue;
      int slot = (b == 0) ? (c * QS + q) : (4 * QS + (c - 4));
      l += lP[(size_t)slot * N_NODES + i];
      const float* ap = &accP[((size_t)slot * N_NODES + i) * 64 + (f0 & 63)];
      f32x4 v0 = *(const f32x4*)ap, v1 = *(const f32x4*)(ap + 4);
#pragma unroll
      for (int e = 0; e < 4; ++e) { a[e] += v0[e]; a[e + 4] += v1[e]; }
    }
  }
  float inv = (l > 0.f) ? 1.f / l : 0.f;
  bf16x8 o;
#pragma unroll
  for (int e = 0; e < 8; ++e) {
    float v = (l > 0.f) ? a[e] * inv : gm[f0 + e];
    v += feat[(size_t)i * D_IN + fi + e];
    o[e] = (bf16)v;
  }
  *(bf16x8*)&fused[(size_t)i * C2 + (2 - b) * D_IN + fi] = o;
}

// ---------------------------------------------------------------- launch
extern "C" void kernel_launch(void* const* d_in, const int* in_sizes, int n_in,
                              void* d_out, int out_size, void* d_ws, size_t ws_size,
                              hipStream_t stream) {
  (void)in_sizes; (void)n_in; (void)out_size; (void)ws_size;
  const float* feature = (const float*)d_in[0];
  const int*   adj     = (const int*)d_in[1];
  const int*   dnum    = (const int*)d_in[2];
  const int*   snum    = (const int*)d_in[3];
  const float* W1s = (const float*)d_in[4];  const float* a1s = (const float*)d_in[5];
  const float* W2s = (const float*)d_in[6];  const float* a2s = (const float*)d_in[7];
  const float* W1e = (const float*)d_in[8];  const float* a1e = (const float*)d_in[9];
  const float* W2e = (const float*)d_in[10]; const float* a2e = (const float*)d_in[11];
  const float* W1d = (const float*)d_in[12]; const float* a1d = (const float*)d_in[13];
  const float* W2d = (const float*)d_in[14]; const float* a2d = (const float*)d_in[15];
  const float* fW  = (const float*)d_in[16]; const float* fB  = (const float*)d_in[17];
  const float* w0  = (const float*)d_in[18]; const float* b0  = (const float*)d_in[19];
  const float* w1  = (const float*)d_in[20]; const float* b1  = (const float*)d_in[21];
  const float* w2  = (const float*)d_in[22]; const float* b2  = (const float*)d_in[23];

  char* ws = (char*)d_ws;
  size_t off = 0;
  auto alloc = [&](size_t bytes) { void* p = ws + off; off += (bytes + 255) & ~(size_t)255; return p; };

  unsigned char* adjT = (unsigned char*)alloc((size_t)384 * N_NODES);  // [mo][row], 1.125 MB
  bf16* fbf   = (bf16*)alloc((size_t)N_NODES * D_IN * 2);
  bf16* w1b0  = (bf16*)alloc(HIDDEN * D_IN * 2);
  bf16* w1b1  = (bf16*)alloc(HIDDEN * D_IN * 2);
  bf16* w1b2  = (bf16*)alloc(HIDDEN * D_IN * 2);
  bf16* w2b0  = (bf16*)alloc(D_IN * HIDDEN * 2);
  bf16* w2b1  = (bf16*)alloc(D_IN * HIDDEN * 2);
  bf16* w2b2  = (bf16*)alloc(D_IN * HIDDEN * 2);
  bf16* wfusb = (bf16*)alloc(D_IN * C2 * 2);
  bf16* wf0b  = (bf16*)alloc(HIDDEN * D_IN * 2);
  bf16* wf1b  = (bf16*)alloc(HIDDEN * HIDDEN * 2);
  bf16* wf2b  = (bf16*)alloc(D_IN * HIDDEN * 2);
  bf16* g1    = (bf16*)alloc((size_t)N_NODES * C1 * 2);
  bf16* gP1   = (bf16*)alloc((size_t)N_NODES * C1 * 2);
  bf16* out1  = (bf16*)alloc((size_t)N_NODES * C1 * 2);
  bf16* g2    = (bf16*)alloc((size_t)N_NODES * C2 * 2);
  bf16* gP2   = (bf16*)alloc((size_t)N_NODES * C2 * 2);
  bf16* fusedB= (bf16*)alloc((size_t)N_NODES * C2 * 2);
  bf16* h0    = (bf16*)alloc((size_t)N_NODES * D_IN * 2);
  bf16* h1    = (bf16*)alloc((size_t)N_NODES * HIDDEN * 2);
  bf16* h2    = (bf16*)alloc((size_t)N_NODES * HIDDEN * 2);
  float* elp1 = (float*)alloc(18 * N_NODES * 4);
  float* eln1 = (float*)alloc(18 * N_NODES * 4);
  float* erp1 = (float*)alloc(18 * N_NODES * 4);
  float* ern1 = (float*)alloc(18 * N_NODES * 4);
  float* elp2 = (float*)alloc(3 * N_NODES * 4);
  float* eln2 = (float*)alloc(3 * N_NODES * 4);
  float* erp2 = (float*)alloc(3 * N_NODES * 4);
  float* ern2 = (float*)alloc(3 * N_NODES * 4);
  // partial slots: att1 = 6*QS+12 = 60, att2 = 4*QS+8 = 40 -> union 60
  float* accU = (float*)alloc((size_t)(6 * QS + 12) * N_NODES * 64 * 4);  // 47 MB
  float* lU   = (float*)alloc((size_t)(6 * QS + 12) * N_NODES * 4);
  size_t zoff = off;
  float* gm1  = (float*)alloc(C1 * 4);
  float* gm2  = (float*)alloc(C2 * 4);
  size_t zbytes = off - zoff;

  hipMemsetAsync(ws + zoff, 0, zbytes, stream);

  // 1) casts + adj transpose (merged)
  CastArgs ca;
  {
    const float* srcs[11] = { feature, W1s, W1e, W1d, W2s, W2e, W2d, fW, w0, w1, w2 };
    bf16* dsts[11] = { fbf, w1b0, w1b1, w1b2, w2b0, w2b1, w2b2, wfusb, wf0b, wf1b, wf2b };
    int counts[11] = { N_NODES*D_IN, HIDDEN*D_IN, HIDDEN*D_IN, HIDDEN*D_IN,
                       D_IN*HIDDEN, D_IN*HIDDEN, D_IN*HIDDEN, D_IN*C2,
                       HIDDEN*D_IN, HIDDEN*HIDDEN, D_IN*HIDDEN };
    int cum = 0;
    for (int k = 0; k < 11; ++k) { ca.src[k] = srcs[k]; ca.dst[k] = dsts[k]; ca.cum4[k] = cum; cum += counts[k] / 4; }
    ca.cum4[11] = cum;
    ca.castN = cum / 256;
    prep_kernel<<<ca.castN + 288, 256, 0, stream>>>(ca, adj, adjT);
  }
  // 2) g1 = f @ W1^T (3 branches via z)
  gemm32_kernel<false,false,false,false><<<dim3(96,6,3), 256, 0, stream>>>(
      fbf, D_IN, 0, w1b0, w1b1, w1b2, D_IN, g1, C1, HIDDEN, D_IN, nullptr, nullptr);
  // 3) pack g1 -> gP1 (+colmean +layer1 head-proj fold)
  pack_kernel<C1,true><<<dim3(48,18), 256, 0, stream>>>(g1, gP1, gm1, a1s, a1e, a1d, elp1, eln1, erp1, ern1);
  // 4) attention 1 partials (LDS-staged 2-phase)
  att_kernel<true><<<dim3(12, 18, QS), 256, 0, stream>>>(gP1, elp1, eln1, erp1, ern1, adjT, dnum, snum, accU, lU);
  // 4b) finalize 1 (+ELU)
  fin1_kernel<<<N_NODES * (C1 / 8) / 256, 256, 0, stream>>>(accU, lU, gm1, dnum, snum, out1);
  // 5) g2 = out1 @ W2^T per branch
  gemm32_kernel<false,false,false,false><<<dim3(96,4,3), 256, 0, stream>>>(
      out1, C1, HIDDEN, w2b0, w2b1, w2b2, HIDDEN, g2, C2, D_IN, HIDDEN, nullptr, nullptr);
  // 6) pack g2 -> gP2 (+colmean) + layer2 head-proj (merged, 1D grid)
  pack2_proj_kernel<<<1152, 256, 0, stream>>>(g2, gP2, gm2, a2s, a2e, a2d, elp2, eln2, erp2, ern2);
  // 7) attention 2 partials
  att_kernel<false><<<dim3(12, 12, QS), 256, 0, stream>>>(gP2, elp2, eln2, erp2, ern2, adjT, dnum, snum, accU, lU);
  // 7b) finalize 2 (+residual, writes fused [doc,sect,sent])
  fin2_kernel<<<N_NODES * (C2 / 8) / 256, 256, 0, stream>>>(accU, lU, gm2, feature, dnum, snum, fusedB);
  // 8) fusion: h0 = leaky(fused @ fW^T + fB)
  gemm32_kernel<true,true,false,false><<<dim3(96,4,1), 256, 0, stream>>>(
      fusedB, C2, 0, wfusb, wfusb, wfusb, C2, h0, D_IN, 0, C2, fB, nullptr);
  // 9) ffn0: h1 = leaky(h0 @ w0^T + b0)
  gemm32_kernel<true,true,false,false><<<dim3(96,6,1), 256, 0, stream>>>(
      h0, D_IN, 0, wf0b, wf0b, wf0b, D_IN, h1, HIDDEN, 0, D_IN, b0, nullptr);
  // 10) ffn1: h2 = leaky(h1 @ w1^T + b1)
  gemm32_kernel<true,true,false,false><<<dim3(96,6,1), 256, 0, stream>>>(
      h1, HIDDEN, 0, wf1b, wf1b, wf1b, HIDDEN, h2, HIDDEN, 0, HIDDEN, b1, nullptr);
  // 11) ffn2: out = leaky(h2 @ w2^T + b2) + f   (fp32 out)
  gemm32_kernel<true,true,true,true><<<dim3(96,4,1), 256, 0, stream>>>(
      h2, HIDDEN, 0, wf2b, wf2b, wf2b, HIDDEN, d_out, D_IN, 0, HIDDEN, b2, feature);
}